// Round 1
// baseline (860.782 us; speedup 1.0000x reference)
//
#include <hip/hip_runtime.h>

#define B_ 8
#define C_ 256
#define N_ 4096
#define R_ 64
#define STEPS_ 7
#define KS_ 32
#define EPS_ 1e-6f

// ---------------- 1x1 conv: out[b,o,n] = sum_c w[o,c]*in[b,c,n] (+bias, relu) ----
template<bool BIAS_RELU>
__global__ __launch_bounds__(256)
void conv1x1_kernel(const float* __restrict__ in, const float* __restrict__ w,
                    const float* __restrict__ bias, float* __restrict__ out) {
  const int n0 = blockIdx.x * 256;
  const int o0 = blockIdx.y * 64;
  const int b  = blockIdx.z;
  const float* inb = in + (size_t)b * C_ * N_;
  float* outb = out + (size_t)b * C_ * N_;
  __shared__ float w_s[64][16];
  __shared__ float in_s[16][256];
  const int t = threadIdx.x;
  const int tx = t & 63;
  const int ty = t >> 6;
  float acc[16][4];
#pragma unroll
  for (int i = 0; i < 16; ++i) { acc[i][0]=0.f; acc[i][1]=0.f; acc[i][2]=0.f; acc[i][3]=0.f; }
  const int lo = t >> 2;
  const int lk = (t & 3) * 4;
  const int ln = (t & 63) * 4;
  const int lkk = t >> 6;
  for (int kt = 0; kt < C_; kt += 16) {
    *(float4*)&w_s[lo][lk] = *(const float4*)&w[(size_t)(o0 + lo) * C_ + kt + lk];
#pragma unroll
    for (int p = 0; p < 4; ++p) {
      *(float4*)&in_s[lkk + 4*p][ln] =
          *(const float4*)&inb[(size_t)(kt + lkk + 4*p) * N_ + n0 + ln];
    }
    __syncthreads();
#pragma unroll
    for (int k = 0; k < 16; ++k) {
      float4 bv = *(const float4*)&in_s[k][tx * 4];
#pragma unroll
      for (int i = 0; i < 16; ++i) {
        float a = w_s[ty * 16 + i][k];
        acc[i][0] = fmaf(a, bv.x, acc[i][0]);
        acc[i][1] = fmaf(a, bv.y, acc[i][1]);
        acc[i][2] = fmaf(a, bv.z, acc[i][2]);
        acc[i][3] = fmaf(a, bv.w, acc[i][3]);
      }
    }
    __syncthreads();
  }
#pragma unroll
  for (int i = 0; i < 16; ++i) {
    const int o = o0 + ty * 16 + i;
    float4 v = make_float4(acc[i][0], acc[i][1], acc[i][2], acc[i][3]);
    if (BIAS_RELU) {
      const float bb = bias[o];
      v.x = fmaxf(v.x + bb, 0.f); v.y = fmaxf(v.y + bb, 0.f);
      v.z = fmaxf(v.z + bb, 0.f); v.w = fmaxf(v.w + bb, 0.f);
    }
    *(float4*)&outb[(size_t)o * N_ + n0 + tx * 4] = v;
  }
}

// ---------------- normalize bases over d ----------------
__global__ __launch_bounds__(256)
void norm_bases_kernel(const float* __restrict__ binit, float* __restrict__ bases) {
  const int b = blockIdx.x;
  const int t = threadIdx.x;
  const int rr = t & 63;
  const int dq = t >> 6;
  const float* src = binit + (size_t)b * C_ * R_;
  float* dst = bases + (size_t)b * C_ * R_;
  float vals[64];
  float s = 0.f;
#pragma unroll
  for (int i = 0; i < 64; ++i) {
    float v = src[(size_t)(dq + 4*i) * R_ + rr];
    vals[i] = v;
    s = fmaf(v, v, s);
  }
  __shared__ float red[4][64];
  red[dq][rr] = s;
  __syncthreads();
  float nrm = red[0][rr] + red[1][rr] + red[2][rr] + red[3][rr];
  nrm = fmaxf(sqrtf(nrm), 1e-12f);
  const float inv = 1.f / nrm;
#pragma unroll
  for (int i = 0; i < 64; ++i) dst[(size_t)(dq + 4*i) * R_ + rr] = vals[i] * inv;
}

// ---------------- coef init (softmax) / coef update (multiplicative) ----------
// num[n,r] = sum_d xm[d,n]*bases[d,r]; UPDATE: den[n,r]=sum_k coef[n,k]*btb[k,r]
template<bool UPDATE>
__global__ __launch_bounds__(256)
void coef_kernel(const float* __restrict__ xm, const float* __restrict__ bases,
                 const float* __restrict__ btbp, float* __restrict__ coef) {
  const int n0 = blockIdx.x * 64;
  const int b  = blockIdx.y;
  const float* xb = xm + (size_t)b * C_ * N_;
  const float* bb = bases + (size_t)b * C_ * R_;
  float* cb = coef + (size_t)b * N_ * R_;
  __shared__ float x_s[64][64];
  __shared__ float b_s[64][64];
  __shared__ float c_s[64][65];
  __shared__ float t_s[64][64];
  const int t = threadIdx.x;
  const int tq = t & 15;
  const int tn = t >> 4;
  const int r0 = tq * 4;
  const int lc = t & 63;
  const int lr = t >> 6;
  float num[4][4];
#pragma unroll
  for (int i = 0; i < 4; ++i) { num[i][0]=0.f; num[i][1]=0.f; num[i][2]=0.f; num[i][3]=0.f; }

  for (int d0 = 0; d0 < C_; d0 += 64) {
#pragma unroll
    for (int p = 0; p < 16; ++p) {
      x_s[lr + 4*p][lc] = xb[(size_t)(d0 + lr + 4*p) * N_ + n0 + lc];
      b_s[lr + 4*p][lc] = bb[(size_t)(d0 + lr + 4*p) * R_ + lc];
    }
    __syncthreads();
#pragma unroll
    for (int dd = 0; dd < 64; ++dd) {
      float4 bv = *(const float4*)&b_s[dd][r0];
#pragma unroll
      for (int i = 0; i < 4; ++i) {
        float a = x_s[dd][tn + 16*i];
        num[i][0] = fmaf(a, bv.x, num[i][0]);
        num[i][1] = fmaf(a, bv.y, num[i][1]);
        num[i][2] = fmaf(a, bv.z, num[i][2]);
        num[i][3] = fmaf(a, bv.w, num[i][3]);
      }
    }
    __syncthreads();
  }

  if (UPDATE) {
#pragma unroll
    for (int p = 0; p < 16; ++p) {
      const int row = lr + 4*p;
      c_s[row][lc] = cb[(size_t)(n0 + row) * R_ + lc];
      float v = 0.f;
#pragma unroll
      for (int s = 0; s < 4; ++s)
        v += btbp[((size_t)b * 4 + s) * (R_ * R_) + row * R_ + lc];
      t_s[row][lc] = v;
    }
    __syncthreads();
    float den[4][4];
#pragma unroll
    for (int i = 0; i < 4; ++i) { den[i][0]=0.f; den[i][1]=0.f; den[i][2]=0.f; den[i][3]=0.f; }
#pragma unroll
    for (int k = 0; k < 64; ++k) {
      float4 tv = *(const float4*)&t_s[k][r0];
#pragma unroll
      for (int i = 0; i < 4; ++i) {
        float cv = c_s[tn + 16*i][k];
        den[i][0] = fmaf(cv, tv.x, den[i][0]);
        den[i][1] = fmaf(cv, tv.y, den[i][1]);
        den[i][2] = fmaf(cv, tv.z, den[i][2]);
        den[i][3] = fmaf(cv, tv.w, den[i][3]);
      }
    }
#pragma unroll
    for (int i = 0; i < 4; ++i) {
      const int row = tn + 16*i;
      float4 o;
      o.x = c_s[row][r0+0] * num[i][0] / (den[i][0] + EPS_);
      o.y = c_s[row][r0+1] * num[i][1] / (den[i][1] + EPS_);
      o.z = c_s[row][r0+2] * num[i][2] / (den[i][2] + EPS_);
      o.w = c_s[row][r0+3] * num[i][3] / (den[i][3] + EPS_);
      *(float4*)&cb[(size_t)(n0 + row) * R_ + r0] = o;
    }
  } else {
#pragma unroll
    for (int i = 0; i < 4; ++i) {
      float m = fmaxf(fmaxf(num[i][0], num[i][1]), fmaxf(num[i][2], num[i][3]));
#pragma unroll
      for (int off = 1; off < 16; off <<= 1) m = fmaxf(m, __shfl_xor(m, off));
      float e0 = __expf(num[i][0]-m), e1 = __expf(num[i][1]-m);
      float e2 = __expf(num[i][2]-m), e3 = __expf(num[i][3]-m);
      float s = e0+e1+e2+e3;
#pragma unroll
      for (int off = 1; off < 16; off <<= 1) s += __shfl_xor(s, off);
      const float inv = 1.f / s;
      const int row = tn + 16*i;
      *(float4*)&cb[(size_t)(n0 + row) * R_ + r0] = make_float4(e0*inv, e1*inv, e2*inv, e3*inv);
    }
  }
}

// ---------------- btb partial: btbp[b,ds,r,k] = sum over 64 d of bases ----------
__global__ __launch_bounds__(256)
void btb_part_kernel(const float* __restrict__ bases, float* __restrict__ btbp) {
  const int ds = blockIdx.x;
  const int b  = blockIdx.y;
  const float* bb = bases + (size_t)b * C_ * R_ + (size_t)ds * 64 * R_;
  __shared__ float b_s[64][64];
  const int t = threadIdx.x;
  const int tq = t & 15, tn = t >> 4, k0 = tq * 4;
  const int lc = t & 63, lr = t >> 6;
#pragma unroll
  for (int p = 0; p < 16; ++p)
    b_s[lr + 4*p][lc] = bb[(size_t)(lr + 4*p) * R_ + lc];
  __syncthreads();
  float acc[4][4];
#pragma unroll
  for (int i = 0; i < 4; ++i) { acc[i][0]=0.f; acc[i][1]=0.f; acc[i][2]=0.f; acc[i][3]=0.f; }
#pragma unroll
  for (int dd = 0; dd < 64; ++dd) {
    float4 kv = *(const float4*)&b_s[dd][k0];
#pragma unroll
    for (int i = 0; i < 4; ++i) {
      float rv = b_s[dd][tn + 16*i];
      acc[i][0] = fmaf(rv, kv.x, acc[i][0]);
      acc[i][1] = fmaf(rv, kv.y, acc[i][1]);
      acc[i][2] = fmaf(rv, kv.z, acc[i][2]);
      acc[i][3] = fmaf(rv, kv.w, acc[i][3]);
    }
  }
  float* ob = btbp + ((size_t)b * 4 + ds) * (R_ * R_);
#pragma unroll
  for (int i = 0; i < 4; ++i)
    *(float4*)&ob[(tn + 16*i) * R_ + k0] = make_float4(acc[i][0], acc[i][1], acc[i][2], acc[i][3]);
}

// ---------------- ctc partial over 128 n ----------------
__global__ __launch_bounds__(256)
void ctc_part_kernel(const float* __restrict__ coef, float* __restrict__ ctcp) {
  const int ks = blockIdx.x;
  const int b  = blockIdx.y;
  const float* cb = coef + (size_t)b * N_ * R_;
  __shared__ float c_s[64][64];
  const int t = threadIdx.x;
  const int tq = t & 15, tn = t >> 4, k0 = tq * 4;
  const int lc = t & 63, lr = t >> 6;
  float acc[4][4];
#pragma unroll
  for (int i = 0; i < 4; ++i) { acc[i][0]=0.f; acc[i][1]=0.f; acc[i][2]=0.f; acc[i][3]=0.f; }
  for (int nt = 0; nt < 2; ++nt) {
    const int n0 = ks * 128 + nt * 64;
#pragma unroll
    for (int p = 0; p < 16; ++p)
      c_s[lr + 4*p][lc] = cb[(size_t)(n0 + lr + 4*p) * R_ + lc];
    __syncthreads();
#pragma unroll
    for (int nn = 0; nn < 64; ++nn) {
      float4 kv = *(const float4*)&c_s[nn][k0];
#pragma unroll
      for (int i = 0; i < 4; ++i) {
        float rv = c_s[nn][tn + 16*i];
        acc[i][0] = fmaf(rv, kv.x, acc[i][0]);
        acc[i][1] = fmaf(rv, kv.y, acc[i][1]);
        acc[i][2] = fmaf(rv, kv.z, acc[i][2]);
        acc[i][3] = fmaf(rv, kv.w, acc[i][3]);
      }
    }
    __syncthreads();
  }
  float* ob = ctcp + ((size_t)b * KS_ + ks) * (R_ * R_);
#pragma unroll
  for (int i = 0; i < 4; ++i)
    *(float4*)&ob[(tn + 16*i) * R_ + k0] = make_float4(acc[i][0], acc[i][1], acc[i][2], acc[i][3]);
}

// ---------------- x@coef partial: xcp[b,ks,d,r] over 128 n ----------------
__global__ __launch_bounds__(256)
void xcoef_part_kernel(const float* __restrict__ xm, const float* __restrict__ coef,
                       float* __restrict__ xcp) {
  const int dt = blockIdx.x;
  const int ks = blockIdx.y;
  const int b  = blockIdx.z;
  const int d0 = dt * 64;
  const float* xb = xm + (size_t)b * C_ * N_;
  const float* cb = coef + (size_t)b * N_ * R_;
  __shared__ float x_s[64][65];
  __shared__ float c_s[64][64];
  const int t = threadIdx.x;
  const int tq = t & 15, tn = t >> 4, r0 = tq * 4;
  const int lc = t & 63, lr = t >> 6;
  float acc[4][4];
#pragma unroll
  for (int i = 0; i < 4; ++i) { acc[i][0]=0.f; acc[i][1]=0.f; acc[i][2]=0.f; acc[i][3]=0.f; }
  for (int nt = 0; nt < 2; ++nt) {
    const int n0 = ks * 128 + nt * 64;
#pragma unroll
    for (int p = 0; p < 16; ++p) {
      x_s[lr + 4*p][lc] = xb[(size_t)(d0 + lr + 4*p) * N_ + n0 + lc];
      c_s[lr + 4*p][lc] = cb[(size_t)(n0 + lr + 4*p) * R_ + lc];
    }
    __syncthreads();
#pragma unroll
    for (int nn = 0; nn < 64; ++nn) {
      float4 cv = *(const float4*)&c_s[nn][r0];
#pragma unroll
      for (int i = 0; i < 4; ++i) {
        float a = x_s[tn + 16*i][nn];
        acc[i][0] = fmaf(a, cv.x, acc[i][0]);
        acc[i][1] = fmaf(a, cv.y, acc[i][1]);
        acc[i][2] = fmaf(a, cv.z, acc[i][2]);
        acc[i][3] = fmaf(a, cv.w, acc[i][3]);
      }
    }
    __syncthreads();
  }
  float* ob = xcp + ((size_t)b * KS_ + ks) * (C_ * R_) + (size_t)d0 * R_;
#pragma unroll
  for (int i = 0; i < 4; ++i)
    *(float4*)&ob[(tn + 16*i) * R_ + r0] = make_float4(acc[i][0], acc[i][1], acc[i][2], acc[i][3]);
}

// ---------------- bases update: bases *= num2 / (bases@ctc + eps) ----------------
__global__ __launch_bounds__(1024)
void bases_update_kernel(const float* __restrict__ xcp, const float* __restrict__ ctcp,
                         float* __restrict__ bases) {
  const int dt = blockIdx.x;
  const int b  = blockIdx.y;
  const int d0 = dt * 64;
  float* bb = bases + (size_t)b * C_ * R_;
  __shared__ float ctc_s[64 * 64];
  __shared__ float b_s[64][65];
  const int t = threadIdx.x;
  const int tq = t & 15;
  const int dd = t >> 4;
  const int r0 = tq * 4;
  {
    float4 a = make_float4(0,0,0,0);
    for (int s = 0; s < KS_; ++s) {
      float4 v = *(const float4*)&ctcp[((size_t)b * KS_ + s) * (R_*R_) + t * 4];
      a.x += v.x; a.y += v.y; a.z += v.z; a.w += v.w;
    }
    *(float4*)&ctc_s[t * 4] = a;
  }
  {
    const int lc = t & 63, lr = t >> 6;  // lr in 0..15
#pragma unroll
    for (int p = 0; p < 4; ++p)
      b_s[lr + 16*p][lc] = bb[(size_t)(d0 + lr + 16*p) * R_ + lc];
  }
  float4 num2 = make_float4(0,0,0,0);
  for (int s = 0; s < KS_; ++s) {
    float4 v = *(const float4*)&xcp[(((size_t)b * KS_ + s) * C_ + d0 + dd) * R_ + r0];
    num2.x += v.x; num2.y += v.y; num2.z += v.z; num2.w += v.w;
  }
  __syncthreads();
  float4 den = make_float4(0,0,0,0);
#pragma unroll
  for (int k = 0; k < 64; ++k) {
    const float a = b_s[dd][k];
    float4 cv = *(const float4*)&ctc_s[k * 64 + r0];
    den.x = fmaf(a, cv.x, den.x); den.y = fmaf(a, cv.y, den.y);
    den.z = fmaf(a, cv.z, den.z); den.w = fmaf(a, cv.w, den.w);
  }
  float4 o;
  o.x = b_s[dd][r0+0] * num2.x / (den.x + EPS_);
  o.y = b_s[dd][r0+1] * num2.y / (den.y + EPS_);
  o.z = b_s[dd][r0+2] * num2.z / (den.z + EPS_);
  o.w = b_s[dd][r0+3] * num2.w / (den.w + EPS_);
  *(float4*)&bb[(size_t)(d0 + dd) * R_ + r0] = o;
}

// ---------------- rec[d,n] = sum_r bases[d,r]*coef[n,r] ----------------
__global__ __launch_bounds__(256)
void rec_kernel(const float* __restrict__ bases, const float* __restrict__ coef,
                float* __restrict__ rec) {
  const int n0 = blockIdx.x * 64;
  const int d0 = blockIdx.y * 64;
  const int b  = blockIdx.z;
  const float* bb = bases + (size_t)b * C_ * R_;
  const float* cb = coef + (size_t)b * N_ * R_;
  float* ob = rec + (size_t)b * C_ * N_;
  __shared__ float b_s[64][65];
  __shared__ float cT[64][65];
  const int t = threadIdx.x;
  const int tq = t & 15, tn = t >> 4, nq = tq * 4;
  const int lc = t & 63, lr = t >> 6;
#pragma unroll
  for (int p = 0; p < 16; ++p) {
    b_s[lr + 4*p][lc] = bb[(size_t)(d0 + lr + 4*p) * R_ + lc];
    cT[lc][lr + 4*p] = cb[(size_t)(n0 + lr + 4*p) * R_ + lc];
  }
  __syncthreads();
  float acc[4][4];
#pragma unroll
  for (int i = 0; i < 4; ++i) { acc[i][0]=0.f; acc[i][1]=0.f; acc[i][2]=0.f; acc[i][3]=0.f; }
#pragma unroll
  for (int r = 0; r < 64; ++r) {
    float c0 = cT[r][nq+0], c1 = cT[r][nq+1], c2 = cT[r][nq+2], c3 = cT[r][nq+3];
#pragma unroll
    for (int i = 0; i < 4; ++i) {
      float a = b_s[tn + 16*i][r];
      acc[i][0] = fmaf(a, c0, acc[i][0]);
      acc[i][1] = fmaf(a, c1, acc[i][1]);
      acc[i][2] = fmaf(a, c2, acc[i][2]);
      acc[i][3] = fmaf(a, c3, acc[i][3]);
    }
  }
#pragma unroll
  for (int i = 0; i < 4; ++i)
    *(float4*)&ob[(size_t)(d0 + tn + 16*i) * N_ + n0 + nq] =
        make_float4(acc[i][0], acc[i][1], acc[i][2], acc[i][3]);
}

// ---------------- GroupNorm stats ----------------
__global__ __launch_bounds__(256)
void gn_stats_kernel(const float* __restrict__ o, float* __restrict__ stats) {
  const int g = blockIdx.x;
  const int b = blockIdx.y;
  const float* p = o + ((size_t)b * C_ + g * 8) * N_;
  const int t = threadIdx.x;
  float s = 0.f, s2 = 0.f;
  for (int i = t; i < 8192; i += 256) {
    float4 v = ((const float4*)p)[i];
    s += v.x + v.y + v.z + v.w;
    s2 = fmaf(v.x, v.x, s2); s2 = fmaf(v.y, v.y, s2);
    s2 = fmaf(v.z, v.z, s2); s2 = fmaf(v.w, v.w, s2);
  }
#pragma unroll
  for (int off = 32; off > 0; off >>= 1) { s += __shfl_down(s, off); s2 += __shfl_down(s2, off); }
  __shared__ float rs[4], rs2[4];
  if ((t & 63) == 0) { rs[t >> 6] = s; rs2[t >> 6] = s2; }
  __syncthreads();
  if (t == 0) {
    float S = rs[0] + rs[1] + rs[2] + rs[3];
    float S2 = rs2[0] + rs2[1] + rs2[2] + rs2[3];
    float mean = S / 32768.f;
    float var = S2 / 32768.f - mean * mean;
    stats[(b * 32 + g) * 2 + 0] = mean;
    stats[(b * 32 + g) * 2 + 1] = rsqrtf(var + 1e-5f);
  }
}

// ---------------- GN affine + residual + relu (in place on d_out) ----------------
__global__ __launch_bounds__(256)
void gn_final_kernel(const float* __restrict__ x, const float* __restrict__ gamma,
                     const float* __restrict__ beta, const float* __restrict__ stats,
                     float* __restrict__ out) {
  const size_t gid = (size_t)blockIdx.x * 256 + threadIdx.x;
  const size_t idx = gid * 4;
  const int b = (int)(idx >> 20);
  const int rem = (int)(idx & ((1u << 20) - 1));
  const int c = rem >> 12;
  const int g = c >> 3;
  const float mean = stats[(b * 32 + g) * 2 + 0];
  const float rstd = stats[(b * 32 + g) * 2 + 1];
  const float ga = gamma[c] * rstd;
  const float be = beta[c] - mean * ga;
  float4 ov = ((const float4*)out)[gid];
  float4 xv = ((const float4*)x)[gid];
  float4 r;
  r.x = fmaxf(fmaf(ov.x, ga, be) + xv.x, 0.f);
  r.y = fmaxf(fmaf(ov.y, ga, be) + xv.y, 0.f);
  r.z = fmaxf(fmaf(ov.z, ga, be) + xv.z, 0.f);
  r.w = fmaxf(fmaf(ov.w, ga, be) + xv.w, 0.f);
  ((float4*)out)[gid] = r;
}

extern "C" void kernel_launch(void* const* d_in, const int* in_sizes, int n_in,
                              void* d_out, int out_size, void* d_ws, size_t ws_size,
                              hipStream_t stream) {
  (void)in_sizes; (void)n_in; (void)out_size; (void)ws_size;
  const float* x      = (const float*)d_in[0];
  const float* w_in   = (const float*)d_in[1];
  const float* b_in   = (const float*)d_in[2];
  const float* w_out  = (const float*)d_in[3];
  const float* gamma  = (const float*)d_in[4];
  const float* beta   = (const float*)d_in[5];
  const float* binit  = (const float*)d_in[6];
  float* out = (float*)d_out;
  float* ws  = (float*)d_ws;

  float* h     = ws;                                     // B*C*N
  float* coef  = h + (size_t)B_ * C_ * N_;               // B*N*R
  float* bases = coef + (size_t)B_ * N_ * R_;            // B*C*R
  float* btbp  = bases + (size_t)B_ * C_ * R_;           // B*4*R*R
  float* ctcp  = btbp + (size_t)B_ * 4 * R_ * R_;        // B*KS*R*R
  float* xcp   = ctcp + (size_t)B_ * KS_ * R_ * R_;      // B*KS*C*R
  float* stats = xcp + (size_t)B_ * KS_ * C_ * R_;       // B*32*2

  conv1x1_kernel<true><<<dim3(N_/256, C_/64, B_), 256, 0, stream>>>(x, w_in, b_in, h);
  norm_bases_kernel<<<dim3(B_), 256, 0, stream>>>(binit, bases);
  coef_kernel<false><<<dim3(N_/64, B_), 256, 0, stream>>>(h, bases, nullptr, coef);

  for (int it = 0; it < STEPS_; ++it) {
    btb_part_kernel<<<dim3(4, B_), 256, 0, stream>>>(bases, btbp);
    coef_kernel<true><<<dim3(N_/64, B_), 256, 0, stream>>>(h, bases, btbp, coef);
    ctc_part_kernel<<<dim3(KS_, B_), 256, 0, stream>>>(coef, ctcp);
    xcoef_part_kernel<<<dim3(4, KS_, B_), 256, 0, stream>>>(h, coef, xcp);
    bases_update_kernel<<<dim3(4, B_), 1024, 0, stream>>>(xcp, ctcp, bases);
  }
  // compute_coef
  btb_part_kernel<<<dim3(4, B_), 256, 0, stream>>>(bases, btbp);
  coef_kernel<true><<<dim3(N_/64, B_), 256, 0, stream>>>(h, bases, btbp, coef);

  rec_kernel<<<dim3(N_/64, C_/64, B_), 256, 0, stream>>>(bases, coef, h);
  conv1x1_kernel<false><<<dim3(N_/256, C_/64, B_), 256, 0, stream>>>(h, w_out, nullptr, out);
  gn_stats_kernel<<<dim3(32, B_), 256, 0, stream>>>(out, stats);
  gn_final_kernel<<<dim3((B_ * C_ * N_) / 4 / 256), 256, 0, stream>>>(x, gamma, beta, stats, out);
}

// Round 2
// 582.547 us; speedup vs baseline: 1.4776x; 1.4776x over previous
//
#include <hip/hip_runtime.h>

#define B_ 8
#define C_ 256
#define N_ 4096
#define R_ 64
#define STEPS_ 7
#define EPS_ 1e-6f

typedef unsigned short u16;
typedef short bf8v __attribute__((ext_vector_type(8)));   // 8 bf16 (4 VGPRs)
typedef float f4v __attribute__((ext_vector_type(4)));    // 4 f32 acc

#define MFMA(a, b, c) __builtin_amdgcn_mfma_f32_16x16x32_bf16((a), (b), (c), 0, 0, 0)

__device__ __forceinline__ u16 bf(float x) {
  union { float f; unsigned u; } v; v.f = x;
  return (u16)((v.u + 0x7FFFu + ((v.u >> 16) & 1u)) >> 16);
}
__device__ __forceinline__ bf8v ldf(const u16* p) { return *(const bf8v*)p; }

// ---------------- weight f32 -> bf16 ----------------
__global__ __launch_bounds__(256)
void cvt_w_kernel(const float* __restrict__ w1, const float* __restrict__ w2,
                  u16* __restrict__ w1b, u16* __restrict__ w2b) {
  const int i = blockIdx.x * 256 + threadIdx.x;
  w1b[i] = bf(w1[i]);
  w2b[i] = bf(w2[i]);
}

// ---------------- x (b,c,n) f32 -> xT (b,n,c) bf16 ----------------
__global__ __launch_bounds__(256)
void xpose_kernel(const float* __restrict__ x, u16* __restrict__ xT) {
  const int n0 = blockIdx.x * 64, c0 = blockIdx.y * 64, b = blockIdx.z;
  __shared__ float lds[64][65];
  const int t = threadIdx.x;
  const float* xb = x + (size_t)b * C_ * N_;
  const int row = t >> 4, col4 = (t & 15) * 4;
#pragma unroll
  for (int p = 0; p < 4; ++p) {
    float4 v = *(const float4*)&xb[(size_t)(c0 + row + 16 * p) * N_ + n0 + col4];
    lds[row + 16 * p][col4 + 0] = v.x; lds[row + 16 * p][col4 + 1] = v.y;
    lds[row + 16 * p][col4 + 2] = v.z; lds[row + 16 * p][col4 + 3] = v.w;
  }
  __syncthreads();
  const int r = t >> 2, cb = (t & 3) * 16;
  __align__(16) u16 tmp[16];
#pragma unroll
  for (int j = 0; j < 16; ++j) tmp[j] = bf(lds[cb + j][r]);
  u16* o = xT + (size_t)b * N_ * C_ + (size_t)(n0 + r) * C_ + c0 + cb;
  *(uint4*)o = *(uint4*)tmp;
  *(uint4*)(o + 8) = *(uint4*)(tmp + 8);
}

// ---------------- normalize bases; write f32 (d,r), bf16 (d,r), bf16 T (r,d) ----
__global__ __launch_bounds__(256)
void norm_bases_kernel(const float* __restrict__ binit, float* __restrict__ bases,
                       u16* __restrict__ bases_bf, u16* __restrict__ basesT) {
  const int b = blockIdx.x, t = threadIdx.x;
  const int rr = t & 63, dq = t >> 6;
  const float* src = binit + (size_t)b * C_ * R_;
  float* dst = bases + (size_t)b * C_ * R_;
  u16* dbf = bases_bf + (size_t)b * C_ * R_;
  u16* dT  = basesT + (size_t)b * R_ * C_;
  float vals[64];
  float s = 0.f;
#pragma unroll
  for (int i = 0; i < 64; ++i) {
    float v = src[(size_t)(dq + 4 * i) * R_ + rr];
    vals[i] = v; s = fmaf(v, v, s);
  }
  __shared__ float red[4][64];
  red[dq][rr] = s;
  __syncthreads();
  float nrm = fmaxf(sqrtf(red[0][rr] + red[1][rr] + red[2][rr] + red[3][rr]), 1e-12f);
  const float inv = 1.f / nrm;
#pragma unroll
  for (int i = 0; i < 64; ++i) {
    const int d = dq + 4 * i;
    const float v = vals[i] * inv;
    dst[(size_t)d * R_ + rr] = v;
    dbf[(size_t)d * R_ + rr] = bf(v);
    dT[(size_t)rr * C_ + d]  = bf(v);
  }
}

// ---------------- conv via MFMA: out[n,o] = sum_k A[n,k]*W[o,k] ----------------
// CONV1: A=xT, W=w_in(o,c), +bias+relu, write h_dn(d,n) bf16 and h_nd(n,d) bf16
// !CONV1: A=rec_nd, W=w_out(o,d), write of32 (o,n) f32
template<bool CONV1>
__global__ __launch_bounds__(256)
void conv_mfma_kernel(const u16* __restrict__ A, const u16* __restrict__ W,
                      const float* __restrict__ bias, u16* __restrict__ h_dn,
                      u16* __restrict__ h_nd, float* __restrict__ of32) {
  const int n0 = blockIdx.x * 64, o0 = blockIdx.y * 64, b = blockIdx.z;
  const int t = threadIdx.x, w = t >> 6, lane = t & 63, g = lane >> 4, c = lane & 15;
  const u16* Ab = A + (size_t)b * N_ * C_ + (size_t)(n0 + w * 16 + c) * C_ + g * 8;
  const u16* Wb = W + (size_t)c * C_ + g * 8;
  f4v acc[4] = {};
  for (int k0 = 0; k0 < C_; k0 += 32) {
    bf8v a = ldf(Ab + k0);
#pragma unroll
    for (int tt = 0; tt < 4; ++tt)
      acc[tt] = MFMA(a, ldf(Wb + (size_t)(o0 + tt * 16) * C_ + k0), acc[tt]);
  }
  __shared__ float lds[64][65];
#pragma unroll
  for (int tt = 0; tt < 4; ++tt) {
    const float bb = CONV1 ? bias[o0 + tt * 16 + c] : 0.f;
#pragma unroll
    for (int rg = 0; rg < 4; ++rg) {
      float v = acc[tt][rg];
      if (CONV1) v = fmaxf(v + bb, 0.f);
      lds[w * 16 + g * 4 + rg][tt * 16 + c] = v;
    }
  }
  __syncthreads();
  if (CONV1) {
    {
      const int n = t >> 2, ob = (t & 3) * 16;
      __align__(16) u16 tmp[16];
#pragma unroll
      for (int j = 0; j < 16; ++j) tmp[j] = bf(lds[n][ob + j]);
      u16* o = h_nd + (size_t)b * N_ * C_ + (size_t)(n0 + n) * C_ + o0 + ob;
      *(uint4*)o = *(uint4*)tmp; *(uint4*)(o + 8) = *(uint4*)(tmp + 8);
    }
    {
      const int oo = t >> 2, nb = (t & 3) * 16;
      __align__(16) u16 tmp[16];
#pragma unroll
      for (int j = 0; j < 16; ++j) tmp[j] = bf(lds[nb + j][oo]);
      u16* o = h_dn + (size_t)b * C_ * N_ + (size_t)(o0 + oo) * N_ + n0 + nb;
      *(uint4*)o = *(uint4*)tmp; *(uint4*)(o + 8) = *(uint4*)(tmp + 8);
    }
  } else {
    const int oo = t >> 2, nb = (t & 3) * 16;
    float* o = of32 + (size_t)b * C_ * N_ + (size_t)(o0 + oo) * N_ + n0 + nb;
#pragma unroll
    for (int q = 0; q < 4; ++q) {
      float4 v = make_float4(lds[nb + q * 4 + 0][oo], lds[nb + q * 4 + 1][oo],
                             lds[nb + q * 4 + 2][oo], lds[nb + q * 4 + 3][oo]);
      *(float4*)&o[q * 4] = v;
    }
  }
}

// ---------------- coef: num=(h^T bases) [+ den=(coef btb), update] or softmax ----
// writes coef f32 (n,r), coef bf16 (n,r), coefT bf16 (r,n)
template<int MODE>  // 0: softmax init, 1: multiplicative update
__global__ __launch_bounds__(256)
void coef_mfma_kernel(const u16* __restrict__ h_nd, const u16* __restrict__ basesT,
                      const u16* __restrict__ btb_bf, float* __restrict__ coef_f32,
                      u16* __restrict__ coef_bf, u16* __restrict__ coefT) {
  const int n0 = blockIdx.x * 64, b = blockIdx.y;
  const int t = threadIdx.x, w = t >> 6, lane = t & 63, g = lane >> 4, c = lane & 15;
  const u16* Ab = h_nd + (size_t)b * N_ * C_ + (size_t)(n0 + w * 16 + c) * C_ + g * 8;
  const u16* Bb = basesT + (size_t)b * R_ * C_ + (size_t)c * C_ + g * 8;
  f4v num[4] = {};
  for (int k0 = 0; k0 < C_; k0 += 32) {
    bf8v a = ldf(Ab + k0);
#pragma unroll
    for (int tt = 0; tt < 4; ++tt)
      num[tt] = MFMA(a, ldf(Bb + (size_t)(tt * 16) * C_ + k0), num[tt]);
  }
  __shared__ float lds[64][65];
  if (MODE == 1) {
    f4v den[4] = {};
    const u16* A2 = coef_bf + (size_t)b * N_ * R_ + (size_t)(n0 + w * 16 + c) * R_ + g * 8;
    const u16* B2 = btb_bf + (size_t)b * R_ * R_ + (size_t)c * R_ + g * 8;
#pragma unroll
    for (int k0 = 0; k0 < R_; k0 += 32) {
      bf8v a2 = ldf(A2 + k0);
#pragma unroll
      for (int tt = 0; tt < 4; ++tt)
        den[tt] = MFMA(a2, ldf(B2 + (size_t)(tt * 16) * R_ + k0), den[tt]);
    }
    const float* cf = coef_f32 + (size_t)b * N_ * R_;
#pragma unroll
    for (int tt = 0; tt < 4; ++tt)
#pragma unroll
      for (int rg = 0; rg < 4; ++rg) {
        const int n = n0 + w * 16 + g * 4 + rg, r = tt * 16 + c;
        const float old = cf[(size_t)n * R_ + r];
        lds[w * 16 + g * 4 + rg][r] = old * num[tt][rg] / (den[tt][rg] + EPS_);
      }
  } else {
#pragma unroll
    for (int rg = 0; rg < 4; ++rg) {
      float m = fmaxf(fmaxf(num[0][rg], num[1][rg]), fmaxf(num[2][rg], num[3][rg]));
#pragma unroll
      for (int off = 1; off < 16; off <<= 1) m = fmaxf(m, __shfl_xor(m, off));
      float e[4], s = 0.f;
#pragma unroll
      for (int tt = 0; tt < 4; ++tt) { e[tt] = __expf(num[tt][rg] - m); s += e[tt]; }
#pragma unroll
      for (int off = 1; off < 16; off <<= 1) s += __shfl_xor(s, off);
      const float inv = 1.f / s;
#pragma unroll
      for (int tt = 0; tt < 4; ++tt) lds[w * 16 + g * 4 + rg][tt * 16 + c] = e[tt] * inv;
    }
  }
  __syncthreads();
  {
    const int n = t >> 2, rb = (t & 3) * 16;
    float* cf = coef_f32 + (size_t)b * N_ * R_ + (size_t)(n0 + n) * R_ + rb;
    u16* cb = coef_bf + (size_t)b * N_ * R_ + (size_t)(n0 + n) * R_ + rb;
    __align__(16) u16 tmp[16];
#pragma unroll
    for (int q = 0; q < 4; ++q) {
      float4 v = make_float4(lds[n][rb + q * 4 + 0], lds[n][rb + q * 4 + 1],
                             lds[n][rb + q * 4 + 2], lds[n][rb + q * 4 + 3]);
      *(float4*)&cf[q * 4] = v;
      tmp[q * 4 + 0] = bf(v.x); tmp[q * 4 + 1] = bf(v.y);
      tmp[q * 4 + 2] = bf(v.z); tmp[q * 4 + 3] = bf(v.w);
    }
    *(uint4*)cb = *(uint4*)tmp; *(uint4*)(cb + 8) = *(uint4*)(tmp + 8);
  }
  {
    const int r = t >> 2, nb = (t & 3) * 16;
    u16* cT = coefT + (size_t)b * R_ * N_ + (size_t)r * N_ + n0 + nb;
    __align__(16) u16 tmp[16];
#pragma unroll
    for (int j = 0; j < 16; ++j) tmp[j] = bf(lds[nb + j][r]);
    *(uint4*)cT = *(uint4*)tmp; *(uint4*)(cT + 8) = *(uint4*)(tmp + 8);
  }
}

// ---------------- btb = bases^T bases (64x64), K=256, bf16 out ----------------
__global__ __launch_bounds__(256)
void btb_mfma_kernel(const u16* __restrict__ basesT, u16* __restrict__ btb_bf) {
  const int b = blockIdx.x;
  const int t = threadIdx.x, w = t >> 6, lane = t & 63, g = lane >> 4, c = lane & 15;
  const u16* base = basesT + (size_t)b * R_ * C_;
  const u16* Ab = base + (size_t)(w * 16 + c) * C_ + g * 8;
  const u16* Bb = base + (size_t)c * C_ + g * 8;
  f4v acc[4] = {};
  for (int k0 = 0; k0 < C_; k0 += 32) {
    bf8v a = ldf(Ab + k0);
#pragma unroll
    for (int tt = 0; tt < 4; ++tt)
      acc[tt] = MFMA(a, ldf(Bb + (size_t)(tt * 16) * C_ + k0), acc[tt]);
  }
  u16* ob = btb_bf + (size_t)b * R_ * R_;
#pragma unroll
  for (int tt = 0; tt < 4; ++tt)
#pragma unroll
    for (int rg = 0; rg < 4; ++rg)
      ob[(size_t)(w * 16 + g * 4 + rg) * R_ + tt * 16 + c] = bf(acc[tt][rg]);
}

// ---------------- ctc partial = coef^T coef over 128 n ----------------
__global__ __launch_bounds__(256)
void ctc_mfma_kernel(const u16* __restrict__ coefT, float* __restrict__ ctcp) {
  const int sp = blockIdx.x, b = blockIdx.y;
  const int t = threadIdx.x, w = t >> 6, lane = t & 63, g = lane >> 4, c = lane & 15;
  const u16* base = coefT + (size_t)b * R_ * N_;
  const u16* Ab = base + (size_t)(w * 16 + c) * N_ + sp * 128 + g * 8;
  const u16* Bb = base + (size_t)c * N_ + sp * 128 + g * 8;
  f4v acc[4] = {};
#pragma unroll
  for (int k0 = 0; k0 < 128; k0 += 32) {
    bf8v a = ldf(Ab + k0);
#pragma unroll
    for (int tt = 0; tt < 4; ++tt)
      acc[tt] = MFMA(a, ldf(Bb + (size_t)(tt * 16) * N_ + k0), acc[tt]);
  }
  float* ob = ctcp + ((size_t)b * 32 + sp) * (R_ * R_);
#pragma unroll
  for (int tt = 0; tt < 4; ++tt)
#pragma unroll
    for (int rg = 0; rg < 4; ++rg)
      ob[(size_t)(w * 16 + g * 4 + rg) * R_ + tt * 16 + c] = acc[tt][rg];
}

// ---------------- xc partial = h coef over 256 n: (d,r) ----------------
__global__ __launch_bounds__(256)
void xc_mfma_kernel(const u16* __restrict__ h_dn, const u16* __restrict__ coefT,
                    float* __restrict__ xcp) {
  const int dt = blockIdx.x, sp = blockIdx.y, b = blockIdx.z;
  const int t = threadIdx.x, w = t >> 6, lane = t & 63, g = lane >> 4, c = lane & 15;
  const u16* Ab = h_dn + (size_t)b * C_ * N_ + (size_t)(dt * 64 + w * 16 + c) * N_ + sp * 256 + g * 8;
  const u16* Bb = coefT + (size_t)b * R_ * N_ + (size_t)c * N_ + sp * 256 + g * 8;
  f4v acc[4] = {};
  for (int k0 = 0; k0 < 256; k0 += 32) {
    bf8v a = ldf(Ab + k0);
#pragma unroll
    for (int tt = 0; tt < 4; ++tt)
      acc[tt] = MFMA(a, ldf(Bb + (size_t)(tt * 16) * N_ + k0), acc[tt]);
  }
  float* ob = xcp + ((size_t)b * 16 + sp) * (C_ * R_);
#pragma unroll
  for (int tt = 0; tt < 4; ++tt)
#pragma unroll
    for (int rg = 0; rg < 4; ++rg)
      ob[(size_t)(dt * 64 + w * 16 + g * 4 + rg) * R_ + tt * 16 + c] = acc[tt][rg];
}

// ---------------- bases *= num2 / (bases@ctc + eps); writes f32+bf16+T ----------
__global__ __launch_bounds__(1024)
void bases_update_kernel(const float* __restrict__ xcp, const float* __restrict__ ctcp,
                         float* __restrict__ bases, u16* __restrict__ bases_bf,
                         u16* __restrict__ basesT) {
  const int dt = blockIdx.x, b = blockIdx.y, d0 = dt * 64;
  float* bb = bases + (size_t)b * C_ * R_;
  __shared__ float ctc_s[64 * 64];
  __shared__ float b_s[64][65];
  const int t = threadIdx.x, tq = t & 15, dd = t >> 4, r0 = tq * 4;
  {
    float4 a = make_float4(0, 0, 0, 0);
    for (int s = 0; s < 32; ++s) {
      float4 v = *(const float4*)&ctcp[((size_t)b * 32 + s) * (R_ * R_) + t * 4];
      a.x += v.x; a.y += v.y; a.z += v.z; a.w += v.w;
    }
    *(float4*)&ctc_s[t * 4] = a;
  }
  {
    const int lc = t & 63, lr = t >> 6;
#pragma unroll
    for (int p = 0; p < 4; ++p)
      b_s[lr + 16 * p][lc] = bb[(size_t)(d0 + lr + 16 * p) * R_ + lc];
  }
  float4 num2 = make_float4(0, 0, 0, 0);
  for (int s = 0; s < 16; ++s) {
    float4 v = *(const float4*)&xcp[(((size_t)b * 16 + s) * C_ + d0 + dd) * R_ + r0];
    num2.x += v.x; num2.y += v.y; num2.z += v.z; num2.w += v.w;
  }
  __syncthreads();
  float4 den = make_float4(0, 0, 0, 0);
#pragma unroll
  for (int k = 0; k < 64; ++k) {
    const float a = b_s[dd][k];
    float4 cv = *(const float4*)&ctc_s[k * 64 + r0];
    den.x = fmaf(a, cv.x, den.x); den.y = fmaf(a, cv.y, den.y);
    den.z = fmaf(a, cv.z, den.z); den.w = fmaf(a, cv.w, den.w);
  }
  float4 o;
  o.x = b_s[dd][r0 + 0] * num2.x / (den.x + EPS_);
  o.y = b_s[dd][r0 + 1] * num2.y / (den.y + EPS_);
  o.z = b_s[dd][r0 + 2] * num2.z / (den.z + EPS_);
  o.w = b_s[dd][r0 + 3] * num2.w / (den.w + EPS_);
  *(float4*)&bb[(size_t)(d0 + dd) * R_ + r0] = o;
  u16* obf = bases_bf + (size_t)b * C_ * R_ + (size_t)(d0 + dd) * R_ + r0;
  obf[0] = bf(o.x); obf[1] = bf(o.y); obf[2] = bf(o.z); obf[3] = bf(o.w);
  u16* oT = basesT + (size_t)b * R_ * C_ + d0 + dd;
  oT[(size_t)(r0 + 0) * C_] = bf(o.x); oT[(size_t)(r0 + 1) * C_] = bf(o.y);
  oT[(size_t)(r0 + 2) * C_] = bf(o.z); oT[(size_t)(r0 + 3) * C_] = bf(o.w);
}

// ---------------- rec_nd[n,d] = sum_r coef[n,r]*bases[d,r], K=64 ----------------
__global__ __launch_bounds__(256)
void rec_mfma_kernel(const u16* __restrict__ coef_bf, const u16* __restrict__ bases_bf,
                     u16* __restrict__ rec_nd) {
  const int n0 = blockIdx.x * 64, d0 = blockIdx.y * 64, b = blockIdx.z;
  const int t = threadIdx.x, w = t >> 6, lane = t & 63, g = lane >> 4, c = lane & 15;
  const u16* Ab = coef_bf + (size_t)b * N_ * R_ + (size_t)(n0 + w * 16 + c) * R_ + g * 8;
  const u16* Bb = bases_bf + (size_t)b * C_ * R_ + (size_t)(d0 + c) * R_ + g * 8;
  f4v acc[4] = {};
#pragma unroll
  for (int k0 = 0; k0 < R_; k0 += 32) {
    bf8v a = ldf(Ab + k0);
#pragma unroll
    for (int tt = 0; tt < 4; ++tt)
      acc[tt] = MFMA(a, ldf(Bb + (size_t)(tt * 16) * R_ + k0), acc[tt]);
  }
  __shared__ float lds[64][65];
#pragma unroll
  for (int tt = 0; tt < 4; ++tt)
#pragma unroll
    for (int rg = 0; rg < 4; ++rg)
      lds[w * 16 + g * 4 + rg][tt * 16 + c] = acc[tt][rg];
  __syncthreads();
  const int n = t >> 2, db = (t & 3) * 16;
  __align__(16) u16 tmp[16];
#pragma unroll
  for (int j = 0; j < 16; ++j) tmp[j] = bf(lds[n][db + j]);
  u16* o = rec_nd + (size_t)b * N_ * C_ + (size_t)(n0 + n) * C_ + d0 + db;
  *(uint4*)o = *(uint4*)tmp; *(uint4*)(o + 8) = *(uint4*)(tmp + 8);
}

// ---------------- GroupNorm stats ----------------
__global__ __launch_bounds__(256)
void gn_stats_kernel(const float* __restrict__ o, float* __restrict__ stats) {
  const int g = blockIdx.x, b = blockIdx.y;
  const float* p = o + ((size_t)b * C_ + g * 8) * N_;
  const int t = threadIdx.x;
  float s = 0.f, s2 = 0.f;
  for (int i = t; i < 8192; i += 256) {
    float4 v = ((const float4*)p)[i];
    s += v.x + v.y + v.z + v.w;
    s2 = fmaf(v.x, v.x, s2); s2 = fmaf(v.y, v.y, s2);
    s2 = fmaf(v.z, v.z, s2); s2 = fmaf(v.w, v.w, s2);
  }
#pragma unroll
  for (int off = 32; off > 0; off >>= 1) { s += __shfl_down(s, off); s2 += __shfl_down(s2, off); }
  __shared__ float rs[4], rs2[4];
  if ((t & 63) == 0) { rs[t >> 6] = s; rs2[t >> 6] = s2; }
  __syncthreads();
  if (t == 0) {
    float S = rs[0] + rs[1] + rs[2] + rs[3];
    float S2 = rs2[0] + rs2[1] + rs2[2] + rs2[3];
    float mean = S / 32768.f;
    float var = S2 / 32768.f - mean * mean;
    stats[(b * 32 + g) * 2 + 0] = mean;
    stats[(b * 32 + g) * 2 + 1] = rsqrtf(var + 1e-5f);
  }
}

// ---------------- GN affine + residual + relu (in place on d_out) ----------------
__global__ __launch_bounds__(256)
void gn_final_kernel(const float* __restrict__ x, const float* __restrict__ gamma,
                     const float* __restrict__ beta, const float* __restrict__ stats,
                     float* __restrict__ out) {
  const size_t gid = (size_t)blockIdx.x * 256 + threadIdx.x;
  const size_t idx = gid * 4;
  const int b = (int)(idx >> 20);
  const int rem = (int)(idx & ((1u << 20) - 1));
  const int c = rem >> 12;
  const int g = c >> 3;
  const float mean = stats[(b * 32 + g) * 2 + 0];
  const float rstd = stats[(b * 32 + g) * 2 + 1];
  const float ga = gamma[c] * rstd;
  const float be = beta[c] - mean * ga;
  float4 ov = ((const float4*)out)[gid];
  float4 xv = ((const float4*)x)[gid];
  float4 r;
  r.x = fmaxf(fmaf(ov.x, ga, be) + xv.x, 0.f);
  r.y = fmaxf(fmaf(ov.y, ga, be) + xv.y, 0.f);
  r.z = fmaxf(fmaf(ov.z, ga, be) + xv.z, 0.f);
  r.w = fmaxf(fmaf(ov.w, ga, be) + xv.w, 0.f);
  ((float4*)out)[gid] = r;
}

extern "C" void kernel_launch(void* const* d_in, const int* in_sizes, int n_in,
                              void* d_out, int out_size, void* d_ws, size_t ws_size,
                              hipStream_t stream) {
  (void)in_sizes; (void)n_in; (void)out_size; (void)ws_size;
  const float* x     = (const float*)d_in[0];
  const float* w_in  = (const float*)d_in[1];
  const float* b_in  = (const float*)d_in[2];
  const float* w_out = (const float*)d_in[3];
  const float* gamma = (const float*)d_in[4];
  const float* beta  = (const float*)d_in[5];
  const float* binit = (const float*)d_in[6];
  float* out = (float*)d_out;

  float* p = (float*)d_ws;
  u16* xT = (u16*)p;            p += 4194304;   // B*N*C bf16; reused as rec_nd later
  u16* rec_nd = xT;
  u16* h_dn = (u16*)p;          p += 4194304;   // B*C*N bf16
  u16* h_nd = (u16*)p;          p += 4194304;   // B*N*C bf16
  float* coef_f32 = p;          p += 2097152;   // B*N*R f32
  u16* coef_bf = (u16*)p;       p += 1048576;   // B*N*R bf16
  u16* coefT = (u16*)p;         p += 1048576;   // B*R*N bf16
  float* bases = p;             p += 131072;    // B*C*R f32
  u16* bases_bf = (u16*)p;      p += 65536;     // B*C*R bf16
  u16* basesT = (u16*)p;        p += 65536;     // B*R*C bf16
  u16* btb_bf = (u16*)p;        p += 16384;     // B*R*R bf16
  float* ctcp = p;              p += 1048576;   // B*32*R*R f32
  float* xcp = p;               p += 2097152;   // B*16*C*R f32
  u16* w1b = (u16*)p;           p += 32768;     // C*C bf16
  u16* w2b = (u16*)p;           p += 32768;     // C*C bf16
  float* stats = p;             p += 512;

  cvt_w_kernel<<<dim3(256), 256, 0, stream>>>(w_in, w_out, w1b, w2b);
  xpose_kernel<<<dim3(64, 4, 8), 256, 0, stream>>>(x, xT);
  norm_bases_kernel<<<dim3(B_), 256, 0, stream>>>(binit, bases, bases_bf, basesT);
  conv_mfma_kernel<true><<<dim3(64, 4, 8), 256, 0, stream>>>(xT, w1b, b_in, h_dn, h_nd, nullptr);
  coef_mfma_kernel<0><<<dim3(64, 8), 256, 0, stream>>>(h_nd, basesT, btb_bf, coef_f32, coef_bf, coefT);

  for (int it = 0; it < STEPS_; ++it) {
    btb_mfma_kernel<<<dim3(8), 256, 0, stream>>>(basesT, btb_bf);
    coef_mfma_kernel<1><<<dim3(64, 8), 256, 0, stream>>>(h_nd, basesT, btb_bf, coef_f32, coef_bf, coefT);
    ctc_mfma_kernel<<<dim3(32, 8), 256, 0, stream>>>(coefT, ctcp);
    xc_mfma_kernel<<<dim3(4, 16, 8), 256, 0, stream>>>(h_dn, coefT, xcp);
    bases_update_kernel<<<dim3(4, 8), 1024, 0, stream>>>(xcp, ctcp, bases, bases_bf, basesT);
  }
  // compute_coef
  btb_mfma_kernel<<<dim3(8), 256, 0, stream>>>(basesT, btb_bf);
  coef_mfma_kernel<1><<<dim3(64, 8), 256, 0, stream>>>(h_nd, basesT, btb_bf, coef_f32, coef_bf, coefT);

  rec_mfma_kernel<<<dim3(64, 4, 8), 256, 0, stream>>>(coef_bf, bases_bf, rec_nd);
  conv_mfma_kernel<false><<<dim3(64, 4, 8), 256, 0, stream>>>(rec_nd, w2b, nullptr, nullptr, nullptr, out);
  gn_stats_kernel<<<dim3(32, 8), 256, 0, stream>>>(out, stats);
  gn_final_kernel<<<dim3((B_ * C_ * N_) / 4 / 256), 256, 0, stream>>>(x, gamma, beta, stats, out);
}

// Round 4
// 545.717 us; speedup vs baseline: 1.5773x; 1.0675x over previous
//
#include <hip/hip_runtime.h>

#define B_ 8
#define C_ 256
#define N_ 4096
#define R_ 64
#define STEPS_ 7
#define EPS_ 1e-6f

typedef unsigned short u16;
typedef short bf8v __attribute__((ext_vector_type(8)));   // 8 bf16 (4 VGPRs)
typedef float f4v __attribute__((ext_vector_type(4)));    // 4 f32 acc

#define MFMA(a, b, c) __builtin_amdgcn_mfma_f32_16x16x32_bf16((a), (b), (c), 0, 0, 0)

__device__ __forceinline__ u16 bf(float x) {
  union { float f; unsigned u; } v; v.f = x;
  return (u16)((v.u + 0x7FFFu + ((v.u >> 16) & 1u)) >> 16);
}
__device__ __forceinline__ bf8v ldf(const u16* p) { return *(const bf8v*)p; }

// ---------------- weight f32 -> bf16 ----------------
__global__ __launch_bounds__(256)
void cvt_w_kernel(const float* __restrict__ w1, const float* __restrict__ w2,
                  u16* __restrict__ w1b, u16* __restrict__ w2b) {
  const int i = blockIdx.x * 256 + threadIdx.x;
  w1b[i] = bf(w1[i]);
  w2b[i] = bf(w2[i]);
}

// ---------------- x (b,c,n) f32 -> xT (b,n,c) bf16 ----------------
__global__ __launch_bounds__(256)
void xpose_kernel(const float* __restrict__ x, u16* __restrict__ xT) {
  const int n0 = blockIdx.x * 64, c0 = blockIdx.y * 64, b = blockIdx.z;
  __shared__ float lds[64][65];
  const int t = threadIdx.x;
  const float* xb = x + (size_t)b * C_ * N_;
  const int row = t >> 4, col4 = (t & 15) * 4;
#pragma unroll
  for (int p = 0; p < 4; ++p) {
    float4 v = *(const float4*)&xb[(size_t)(c0 + row + 16 * p) * N_ + n0 + col4];
    lds[row + 16 * p][col4 + 0] = v.x; lds[row + 16 * p][col4 + 1] = v.y;
    lds[row + 16 * p][col4 + 2] = v.z; lds[row + 16 * p][col4 + 3] = v.w;
  }
  __syncthreads();
  const int r = t >> 2, cb = (t & 3) * 16;
  __align__(16) u16 tmp[16];
#pragma unroll
  for (int j = 0; j < 16; ++j) tmp[j] = bf(lds[cb + j][r]);
  u16* o = xT + (size_t)b * N_ * C_ + (size_t)(n0 + r) * C_ + c0 + cb;
  *(uint4*)o = *(uint4*)tmp;
  *(uint4*)(o + 8) = *(uint4*)(tmp + 8);
}

// ---------------- normalize bases; write f32 (d,r), bf16 (d,r), bf16 T (r,d) ----
__global__ __launch_bounds__(256)
void norm_bases_kernel(const float* __restrict__ binit, float* __restrict__ bases,
                       u16* __restrict__ bases_bf, u16* __restrict__ basesT) {
  const int b = blockIdx.x, t = threadIdx.x;
  const int rr = t & 63, dq = t >> 6;
  const float* src = binit + (size_t)b * C_ * R_;
  float* dst = bases + (size_t)b * C_ * R_;
  u16* dbf = bases_bf + (size_t)b * C_ * R_;
  u16* dT  = basesT + (size_t)b * R_ * C_;
  float vals[64];
  float s = 0.f;
#pragma unroll
  for (int i = 0; i < 64; ++i) {
    float v = src[(size_t)(dq + 4 * i) * R_ + rr];
    vals[i] = v; s = fmaf(v, v, s);
  }
  __shared__ float red[4][64];
  red[dq][rr] = s;
  __syncthreads();
  float nrm = fmaxf(sqrtf(red[0][rr] + red[1][rr] + red[2][rr] + red[3][rr]), 1e-12f);
  const float inv = 1.f / nrm;
#pragma unroll
  for (int i = 0; i < 64; ++i) {
    const int d = dq + 4 * i;
    const float v = vals[i] * inv;
    dst[(size_t)d * R_ + rr] = v;
    dbf[(size_t)d * R_ + rr] = bf(v);
    dT[(size_t)rr * C_ + d]  = bf(v);
  }
}

// ---------------- conv via MFMA: 128x128 block tile, 64x64 per wave ----------------
template<bool CONV1>
__global__ __launch_bounds__(256)
void conv_mfma_kernel(const u16* __restrict__ A, const u16* __restrict__ W,
                      const float* __restrict__ bias, u16* __restrict__ h_dn,
                      u16* __restrict__ h_nd, float* __restrict__ of32) {
  const int nb0 = blockIdx.x * 128, ob0 = blockIdx.y * 128, b = blockIdx.z;
  const int t = threadIdx.x, w = t >> 6, lane = t & 63, g = lane >> 4, c = lane & 15;
  const int n_base = nb0 + (w >> 1) * 64, o_base = ob0 + (w & 1) * 64;
  const u16* Ab = A + (size_t)b * N_ * C_;
  f4v acc[4][4] = {};
  for (int k0 = 0; k0 < C_; k0 += 32) {
    bf8v av[4], wv[4];
#pragma unroll
    for (int mi = 0; mi < 4; ++mi)
      av[mi] = ldf(Ab + (size_t)(n_base + mi * 16 + c) * C_ + k0 + g * 8);
#pragma unroll
    for (int nj = 0; nj < 4; ++nj)
      wv[nj] = ldf(W + (size_t)(o_base + nj * 16 + c) * C_ + k0 + g * 8);
#pragma unroll
    for (int mi = 0; mi < 4; ++mi)
#pragma unroll
      for (int nj = 0; nj < 4; ++nj)
        acc[mi][nj] = MFMA(av[mi], wv[nj], acc[mi][nj]);
  }
  __shared__ float lds[64][65];
  for (int p = 0; p < 4; ++p) {
    if (w == p) {
#pragma unroll
      for (int mi = 0; mi < 4; ++mi)
#pragma unroll
        for (int nj = 0; nj < 4; ++nj) {
          const float bb = CONV1 ? bias[o_base + nj * 16 + c] : 0.f;
#pragma unroll
          for (int rg = 0; rg < 4; ++rg) {
            float v = acc[mi][nj][rg];
            if (CONV1) v = fmaxf(v + bb, 0.f);
            lds[mi * 16 + g * 4 + rg][nj * 16 + c] = v;
          }
        }
    }
    __syncthreads();
    const int pn = nb0 + (p >> 1) * 64, po = ob0 + (p & 1) * 64;
    if (CONV1) {
      {
        const int n = t >> 2, ob2 = (t & 3) * 16;
        __align__(16) u16 tmp[16];
#pragma unroll
        for (int j = 0; j < 16; ++j) tmp[j] = bf(lds[n][ob2 + j]);
        u16* o = h_nd + (size_t)b * N_ * C_ + (size_t)(pn + n) * C_ + po + ob2;
        *(uint4*)o = *(uint4*)tmp; *(uint4*)(o + 8) = *(uint4*)(tmp + 8);
      }
      {
        const int oo = t >> 2, nb2 = (t & 3) * 16;
        __align__(16) u16 tmp[16];
#pragma unroll
        for (int j = 0; j < 16; ++j) tmp[j] = bf(lds[nb2 + j][oo]);
        u16* o = h_dn + (size_t)b * C_ * N_ + (size_t)(po + oo) * N_ + pn + nb2;
        *(uint4*)o = *(uint4*)tmp; *(uint4*)(o + 8) = *(uint4*)(tmp + 8);
      }
    } else {
      const int oo = t >> 2, nb2 = (t & 3) * 16;
      float* o = of32 + (size_t)b * C_ * N_ + (size_t)(po + oo) * N_ + pn + nb2;
#pragma unroll
      for (int q = 0; q < 4; ++q) {
        float4 v = make_float4(lds[nb2 + q * 4 + 0][oo], lds[nb2 + q * 4 + 1][oo],
                               lds[nb2 + q * 4 + 2][oo], lds[nb2 + q * 4 + 3][oo]);
        *(float4*)&o[q * 4] = v;
      }
    }
    __syncthreads();
  }
}

// ---------------- coef: num=(h^T bases) [+ den=(coef btb), update] or softmax ----
// writes coef f32 (n,r), coef bf16 (n,r), coefT bf16 (r,n)
template<int MODE>  // 0: softmax init, 1: multiplicative update
__global__ __launch_bounds__(256)
void coef_mfma_kernel(const u16* __restrict__ h_nd, const u16* __restrict__ basesT,
                      const u16* __restrict__ btb_bf, float* __restrict__ coef_f32,
                      u16* __restrict__ coef_bf, u16* __restrict__ coefT) {
  const int n0 = blockIdx.x * 64, b = blockIdx.y;
  const int t = threadIdx.x, w = t >> 6, lane = t & 63, g = lane >> 4, c = lane & 15;
  const u16* Ab = h_nd + (size_t)b * N_ * C_ + (size_t)(n0 + w * 16 + c) * C_ + g * 8;
  const u16* Bb = basesT + (size_t)b * R_ * C_ + (size_t)c * C_ + g * 8;
  f4v num[4] = {};
  for (int k0 = 0; k0 < C_; k0 += 32) {
    bf8v a = ldf(Ab + k0);
#pragma unroll
    for (int tt = 0; tt < 4; ++tt)
      num[tt] = MFMA(a, ldf(Bb + (size_t)(tt * 16) * C_ + k0), num[tt]);
  }
  __shared__ float lds[64][65];
  if (MODE == 1) {
    f4v den[4] = {};
    const u16* A2 = coef_bf + (size_t)b * N_ * R_ + (size_t)(n0 + w * 16 + c) * R_ + g * 8;
    const u16* B2 = btb_bf + (size_t)b * R_ * R_ + (size_t)c * R_ + g * 8;
#pragma unroll
    for (int k0 = 0; k0 < R_; k0 += 32) {
      bf8v a2 = ldf(A2 + k0);
#pragma unroll
      for (int tt = 0; tt < 4; ++tt)
        den[tt] = MFMA(a2, ldf(B2 + (size_t)(tt * 16) * R_ + k0), den[tt]);
    }
    const float* cf = coef_f32 + (size_t)b * N_ * R_;
#pragma unroll
    for (int tt = 0; tt < 4; ++tt)
#pragma unroll
      for (int rg = 0; rg < 4; ++rg) {
        const int n = n0 + w * 16 + g * 4 + rg, r = tt * 16 + c;
        const float old = cf[(size_t)n * R_ + r];
        lds[w * 16 + g * 4 + rg][r] = old * num[tt][rg] / (den[tt][rg] + EPS_);
      }
  } else {
#pragma unroll
    for (int rg = 0; rg < 4; ++rg) {
      float m = fmaxf(fmaxf(num[0][rg], num[1][rg]), fmaxf(num[2][rg], num[3][rg]));
#pragma unroll
      for (int off = 1; off < 16; off <<= 1) m = fmaxf(m, __shfl_xor(m, off));
      float e[4], s = 0.f;
#pragma unroll
      for (int tt = 0; tt < 4; ++tt) { e[tt] = __expf(num[tt][rg] - m); s += e[tt]; }
#pragma unroll
      for (int off = 1; off < 16; off <<= 1) s += __shfl_xor(s, off);
      const float inv = 1.f / s;
#pragma unroll
      for (int tt = 0; tt < 4; ++tt) lds[w * 16 + g * 4 + rg][tt * 16 + c] = e[tt] * inv;
    }
  }
  __syncthreads();
  {
    const int n = t >> 2, rb = (t & 3) * 16;
    float* cf = coef_f32 + (size_t)b * N_ * R_ + (size_t)(n0 + n) * R_ + rb;
    u16* cb = coef_bf + (size_t)b * N_ * R_ + (size_t)(n0 + n) * R_ + rb;
    __align__(16) u16 tmp[16];
#pragma unroll
    for (int q = 0; q < 4; ++q) {
      float4 v = make_float4(lds[n][rb + q * 4 + 0], lds[n][rb + q * 4 + 1],
                             lds[n][rb + q * 4 + 2], lds[n][rb + q * 4 + 3]);
      *(float4*)&cf[q * 4] = v;
      tmp[q * 4 + 0] = bf(v.x); tmp[q * 4 + 1] = bf(v.y);
      tmp[q * 4 + 2] = bf(v.z); tmp[q * 4 + 3] = bf(v.w);
    }
    *(uint4*)cb = *(uint4*)tmp; *(uint4*)(cb + 8) = *(uint4*)(tmp + 8);
  }
  {
    const int r = t >> 2, nb = (t & 3) * 16;
    u16* cT = coefT + (size_t)b * R_ * N_ + (size_t)r * N_ + n0 + nb;
    __align__(16) u16 tmp[16];
#pragma unroll
    for (int j = 0; j < 16; ++j) tmp[j] = bf(lds[nb + j][r]);
    *(uint4*)cT = *(uint4*)tmp; *(uint4*)(cT + 8) = *(uint4*)(tmp + 8);
  }
}

// ---------------- btb = bases^T bases (64x64), K=256, bf16 out ----------------
__global__ __launch_bounds__(256)
void btb_mfma_kernel(const u16* __restrict__ basesT, u16* __restrict__ btb_bf) {
  const int b = blockIdx.x;
  const int t = threadIdx.x, w = t >> 6, lane = t & 63, g = lane >> 4, c = lane & 15;
  const u16* base = basesT + (size_t)b * R_ * C_;
  const u16* Ab = base + (size_t)(w * 16 + c) * C_ + g * 8;
  const u16* Bb = base + (size_t)c * C_ + g * 8;
  f4v acc[4] = {};
  for (int k0 = 0; k0 < C_; k0 += 32) {
    bf8v a = ldf(Ab + k0);
#pragma unroll
    for (int tt = 0; tt < 4; ++tt)
      acc[tt] = MFMA(a, ldf(Bb + (size_t)(tt * 16) * C_ + k0), acc[tt]);
  }
  u16* ob = btb_bf + (size_t)b * R_ * R_;
#pragma unroll
  for (int tt = 0; tt < 4; ++tt)
#pragma unroll
    for (int rg = 0; rg < 4; ++rg)
      ob[(size_t)(w * 16 + g * 4 + rg) * R_ + tt * 16 + c] = bf(acc[tt][rg]);
}

// ---------------- ctc partial = coef^T coef over 128 n ----------------
__global__ __launch_bounds__(256)
void ctc_mfma_kernel(const u16* __restrict__ coefT, float* __restrict__ ctcp) {
  const int sp = blockIdx.x, b = blockIdx.y;
  const int t = threadIdx.x, w = t >> 6, lane = t & 63, g = lane >> 4, c = lane & 15;
  const u16* base = coefT + (size_t)b * R_ * N_;
  const u16* Ab = base + (size_t)(w * 16 + c) * N_ + sp * 128 + g * 8;
  const u16* Bb = base + (size_t)c * N_ + sp * 128 + g * 8;
  f4v acc[4] = {};
#pragma unroll
  for (int k0 = 0; k0 < 128; k0 += 32) {
    bf8v a = ldf(Ab + k0);
#pragma unroll
    for (int tt = 0; tt < 4; ++tt)
      acc[tt] = MFMA(a, ldf(Bb + (size_t)(tt * 16) * N_ + k0), acc[tt]);
  }
  float* ob = ctcp + ((size_t)b * 32 + sp) * (R_ * R_);
#pragma unroll
  for (int tt = 0; tt < 4; ++tt)
#pragma unroll
    for (int rg = 0; rg < 4; ++rg)
      ob[(size_t)(w * 16 + g * 4 + rg) * R_ + tt * 16 + c] = acc[tt][rg];
}

// ---------------- xc partial = h coef over 256 n: (d,r) ----------------
__global__ __launch_bounds__(256)
void xc_mfma_kernel(const u16* __restrict__ h_dn, const u16* __restrict__ coefT,
                    float* __restrict__ xcp) {
  const int dt = blockIdx.x, sp = blockIdx.y, b = blockIdx.z;
  const int t = threadIdx.x, w = t >> 6, lane = t & 63, g = lane >> 4, c = lane & 15;
  const u16* Ab = h_dn + (size_t)b * C_ * N_ + (size_t)(dt * 64 + w * 16 + c) * N_ + sp * 256 + g * 8;
  const u16* Bb = coefT + (size_t)b * R_ * N_ + (size_t)c * N_ + sp * 256 + g * 8;
  f4v acc[4] = {};
  for (int k0 = 0; k0 < 256; k0 += 32) {
    bf8v a = ldf(Ab + k0);
#pragma unroll
    for (int tt = 0; tt < 4; ++tt)
      acc[tt] = MFMA(a, ldf(Bb + (size_t)(tt * 16) * N_ + k0), acc[tt]);
  }
  float* ob = xcp + ((size_t)b * 16 + sp) * (C_ * R_);
#pragma unroll
  for (int tt = 0; tt < 4; ++tt)
#pragma unroll
    for (int rg = 0; rg < 4; ++rg)
      ob[(size_t)(dt * 64 + w * 16 + g * 4 + rg) * R_ + tt * 16 + c] = acc[tt][rg];
}

// ---------------- bases *= num2 / (bases@ctc + eps); writes f32+bf16+T ----------
__global__ __launch_bounds__(1024)
void bases_update_kernel(const float* __restrict__ xcp, const float* __restrict__ ctcp,
                         float* __restrict__ bases, u16* __restrict__ bases_bf,
                         u16* __restrict__ basesT) {
  const int dt = blockIdx.x, b = blockIdx.y, d0 = dt * 64;
  float* bb = bases + (size_t)b * C_ * R_;
  __shared__ float ctc_s[64 * 64];
  __shared__ float b_s[64][65];
  const int t = threadIdx.x, tq = t & 15, dd = t >> 4, r0 = tq * 4;
  {
    float4 a = make_float4(0, 0, 0, 0);
    for (int s = 0; s < 32; ++s) {
      float4 v = *(const float4*)&ctcp[((size_t)b * 32 + s) * (R_ * R_) + t * 4];
      a.x += v.x; a.y += v.y; a.z += v.z; a.w += v.w;
    }
    *(float4*)&ctc_s[t * 4] = a;
  }
  {
    const int lc = t & 63, lr = t >> 6;
#pragma unroll
    for (int p = 0; p < 4; ++p)
      b_s[lr + 16 * p][lc] = bb[(size_t)(d0 + lr + 16 * p) * R_ + lc];
  }
  float4 num2 = make_float4(0, 0, 0, 0);
  for (int s = 0; s < 16; ++s) {
    float4 v = *(const float4*)&xcp[(((size_t)b * 16 + s) * C_ + d0 + dd) * R_ + r0];
    num2.x += v.x; num2.y += v.y; num2.z += v.z; num2.w += v.w;
  }
  __syncthreads();
  float4 den = make_float4(0, 0, 0, 0);
#pragma unroll
  for (int k = 0; k < 64; ++k) {
    const float a = b_s[dd][k];
    float4 cv = *(const float4*)&ctc_s[k * 64 + r0];
    den.x = fmaf(a, cv.x, den.x); den.y = fmaf(a, cv.y, den.y);
    den.z = fmaf(a, cv.z, den.z); den.w = fmaf(a, cv.w, den.w);
  }
  float4 o;
  o.x = b_s[dd][r0 + 0] * num2.x / (den.x + EPS_);
  o.y = b_s[dd][r0 + 1] * num2.y / (den.y + EPS_);
  o.z = b_s[dd][r0 + 2] * num2.z / (den.z + EPS_);
  o.w = b_s[dd][r0 + 3] * num2.w / (den.w + EPS_);
  *(float4*)&bb[(size_t)(d0 + dd) * R_ + r0] = o;
  u16* obf = bases_bf + (size_t)b * C_ * R_ + (size_t)(d0 + dd) * R_ + r0;
  obf[0] = bf(o.x); obf[1] = bf(o.y); obf[2] = bf(o.z); obf[3] = bf(o.w);
  u16* oT = basesT + (size_t)b * R_ * C_ + d0 + dd;
  oT[(size_t)(r0 + 0) * C_] = bf(o.x); oT[(size_t)(r0 + 1) * C_] = bf(o.y);
  oT[(size_t)(r0 + 2) * C_] = bf(o.z); oT[(size_t)(r0 + 3) * C_] = bf(o.w);
}

// ---------------- rec_nd[n,d] = sum_r coef[n,r]*bases[d,r], K=64 ----------------
__global__ __launch_bounds__(256)
void rec_mfma_kernel(const u16* __restrict__ coef_bf, const u16* __restrict__ bases_bf,
                     u16* __restrict__ rec_nd) {
  const int n0 = blockIdx.x * 64, d0 = blockIdx.y * 64, b = blockIdx.z;
  const int t = threadIdx.x, w = t >> 6, lane = t & 63, g = lane >> 4, c = lane & 15;
  const u16* Ab = coef_bf + (size_t)b * N_ * R_ + (size_t)(n0 + w * 16 + c) * R_ + g * 8;
  const u16* Bb = bases_bf + (size_t)b * C_ * R_ + (size_t)(d0 + c) * R_ + g * 8;
  f4v acc[4] = {};
#pragma unroll
  for (int k0 = 0; k0 < R_; k0 += 32) {
    bf8v a = ldf(Ab + k0);
#pragma unroll
    for (int tt = 0; tt < 4; ++tt)
      acc[tt] = MFMA(a, ldf(Bb + (size_t)(tt * 16) * R_ + k0), acc[tt]);
  }
  __shared__ float lds[64][65];
#pragma unroll
  for (int tt = 0; tt < 4; ++tt)
#pragma unroll
    for (int rg = 0; rg < 4; ++rg)
      lds[w * 16 + g * 4 + rg][tt * 16 + c] = acc[tt][rg];
  __syncthreads();
  const int n = t >> 2, db = (t & 3) * 16;
  __align__(16) u16 tmp[16];
#pragma unroll
  for (int j = 0; j < 16; ++j) tmp[j] = bf(lds[n][db + j]);
  u16* o = rec_nd + (size_t)b * N_ * C_ + (size_t)(n0 + n) * C_ + d0 + db;
  *(uint4*)o = *(uint4*)tmp; *(uint4*)(o + 8) = *(uint4*)(tmp + 8);
}

// ---------------- GroupNorm stats ----------------
__global__ __launch_bounds__(256)
void gn_stats_kernel(const float* __restrict__ o, float* __restrict__ stats) {
  const int g = blockIdx.x, b = blockIdx.y;
  const float* p = o + ((size_t)b * C_ + g * 8) * N_;
  const int t = threadIdx.x;
  float s = 0.f, s2 = 0.f;
  for (int i = t; i < 8192; i += 256) {
    float4 v = ((const float4*)p)[i];
    s += v.x + v.y + v.z + v.w;
    s2 = fmaf(v.x, v.x, s2); s2 = fmaf(v.y, v.y, s2);
    s2 = fmaf(v.z, v.z, s2); s2 = fmaf(v.w, v.w, s2);
  }
#pragma unroll
  for (int off = 32; off > 0; off >>= 1) { s += __shfl_down(s, off); s2 += __shfl_down(s2, off); }
  __shared__ float rs[4], rs2[4];
  if ((t & 63) == 0) { rs[t >> 6] = s; rs2[t >> 6] = s2; }
  __syncthreads();
  if (t == 0) {
    float S = rs[0] + rs[1] + rs[2] + rs[3];
    float S2 = rs2[0] + rs2[1] + rs2[2] + rs2[3];
    float mean = S / 32768.f;
    float var = S2 / 32768.f - mean * mean;
    stats[(b * 32 + g) * 2 + 0] = mean;
    stats[(b * 32 + g) * 2 + 1] = rsqrtf(var + 1e-5f);
  }
}

// ---------------- GN affine + residual + relu (in place on d_out) ----------------
__global__ __launch_bounds__(256)
void gn_final_kernel(const float* __restrict__ x, const float* __restrict__ gamma,
                     const float* __restrict__ beta, const float* __restrict__ stats,
                     float* __restrict__ out) {
  const size_t gid = (size_t)blockIdx.x * 256 + threadIdx.x;
  const size_t idx = gid * 4;
  const int b = (int)(idx >> 20);
  const int rem = (int)(idx & ((1u << 20) - 1));
  const int c = rem >> 12;
  const int g = c >> 3;
  const float mean = stats[(b * 32 + g) * 2 + 0];
  const float rstd = stats[(b * 32 + g) * 2 + 1];
  const float ga = gamma[c] * rstd;
  const float be = beta[c] - mean * ga;
  float4 ov = ((const float4*)out)[gid];
  float4 xv = ((const float4*)x)[gid];
  float4 r;
  r.x = fmaxf(fmaf(ov.x, ga, be) + xv.x, 0.f);
  r.y = fmaxf(fmaf(ov.y, ga, be) + xv.y, 0.f);
  r.z = fmaxf(fmaf(ov.z, ga, be) + xv.z, 0.f);
  r.w = fmaxf(fmaf(ov.w, ga, be) + xv.w, 0.f);
  ((float4*)out)[gid] = r;
}

extern "C" void kernel_launch(void* const* d_in, const int* in_sizes, int n_in,
                              void* d_out, int out_size, void* d_ws, size_t ws_size,
                              hipStream_t stream) {
  (void)in_sizes; (void)n_in; (void)out_size; (void)ws_size;
  const float* x     = (const float*)d_in[0];
  const float* w_in  = (const float*)d_in[1];
  const float* b_in  = (const float*)d_in[2];
  const float* w_out = (const float*)d_in[3];
  const float* gamma = (const float*)d_in[4];
  const float* beta  = (const float*)d_in[5];
  const float* binit = (const float*)d_in[6];
  float* out = (float*)d_out;

  float* p = (float*)d_ws;
  u16* xT = (u16*)p;            p += 4194304;   // B*N*C bf16; reused as rec_nd later
  u16* rec_nd = xT;
  u16* h_dn = (u16*)p;          p += 4194304;   // B*C*N bf16
  u16* h_nd = (u16*)p;          p += 4194304;   // B*N*C bf16
  float* coef_f32 = p;          p += 2097152;   // B*N*R f32
  u16* coef_bf = (u16*)p;       p += 1048576;   // B*N*R bf16
  u16* coefT = (u16*)p;         p += 1048576;   // B*R*N bf16
  float* bases = p;             p += 131072;    // B*C*R f32
  u16* bases_bf = (u16*)p;      p += 65536;     // B*C*R bf16
  u16* basesT = (u16*)p;        p += 65536;     // B*R*C bf16
  u16* btb_bf = (u16*)p;        p += 16384;     // B*R*R bf16
  float* ctcp = p;              p += 1048576;   // B*32*R*R f32
  float* xcp = p;               p += 2097152;   // B*16*C*R f32
  u16* w1b = (u16*)p;           p += 32768;     // C*C bf16
  u16* w2b = (u16*)p;           p += 32768;     // C*C bf16
  float* stats = p;             p += 512;

  cvt_w_kernel<<<dim3(256), 256, 0, stream>>>(w_in, w_out, w1b, w2b);
  xpose_kernel<<<dim3(64, 4, 8), 256, 0, stream>>>(x, xT);
  norm_bases_kernel<<<dim3(B_), 256, 0, stream>>>(binit, bases, bases_bf, basesT);
  conv_mfma_kernel<true><<<dim3(32, 2, 8), 256, 0, stream>>>(xT, w1b, b_in, h_dn, h_nd, nullptr);
  coef_mfma_kernel<0><<<dim3(64, 8), 256, 0, stream>>>(h_nd, basesT, btb_bf, coef_f32, coef_bf, coefT);

  for (int it = 0; it < STEPS_; ++it) {
    btb_mfma_kernel<<<dim3(8), 256, 0, stream>>>(basesT, btb_bf);
    coef_mfma_kernel<1><<<dim3(64, 8), 256, 0, stream>>>(h_nd, basesT, btb_bf, coef_f32, coef_bf, coefT);
    ctc_mfma_kernel<<<dim3(32, 8), 256, 0, stream>>>(coefT, ctcp);
    xc_mfma_kernel<<<dim3(4, 16, 8), 256, 0, stream>>>(h_dn, coefT, xcp);
    bases_update_kernel<<<dim3(4, 8), 1024, 0, stream>>>(xcp, ctcp, bases, bases_bf, basesT);
  }
  // compute_coef
  btb_mfma_kernel<<<dim3(8), 256, 0, stream>>>(basesT, btb_bf);
  coef_mfma_kernel<1><<<dim3(64, 8), 256, 0, stream>>>(h_nd, basesT, btb_bf, coef_f32, coef_bf, coefT);

  rec_mfma_kernel<<<dim3(64, 4, 8), 256, 0, stream>>>(coef_bf, bases_bf, rec_nd);
  conv_mfma_kernel<false><<<dim3(32, 2, 8), 256, 0, stream>>>(rec_nd, w2b, nullptr,
                                                              nullptr, nullptr, out);
  gn_stats_kernel<<<dim3(32, 8), 256, 0, stream>>>(out, stats);
  gn_final_kernel<<<dim3((B_ * C_ * N_) / 4 / 256), 256, 0, stream>>>(x, gamma, beta, stats, out);
}

// Round 5
// 387.548 us; speedup vs baseline: 2.2211x; 1.4081x over previous
//
#include <hip/hip_runtime.h>

#define B_ 8
#define C_ 256
#define N_ 4096
#define R_ 64
#define STEPS_ 7
#define NCH_ 128
#define NSP_ 32
#define EPS_ 1e-6f

typedef unsigned short u16;
typedef short bf8v __attribute__((ext_vector_type(8)));
typedef float f4v __attribute__((ext_vector_type(4)));

#define MFMA(a, b, c) __builtin_amdgcn_mfma_f32_16x16x32_bf16((a), (b), (c), 0, 0, 0)

__device__ __forceinline__ u16 bf(float x) {
  union { float f; unsigned u; } v; v.f = x;
  return (u16)((v.u + 0x7FFFu + ((v.u >> 16) & 1u)) >> 16);
}
__device__ __forceinline__ float bf2f(u16 x) {
  union { unsigned u; float f; } v; v.u = (unsigned)x << 16; return v.f;
}
__device__ __forceinline__ bf8v ldf(const u16* p) { return *(const bf8v*)p; }

// ---------------- weight f32 -> bf16 ----------------
__global__ __launch_bounds__(256)
void cvt_w_kernel(const float* __restrict__ w1, const float* __restrict__ w2,
                  u16* __restrict__ w1b, u16* __restrict__ w2b) {
  const int i = blockIdx.x * 256 + threadIdx.x;
  w1b[i] = bf(w1[i]);
  w2b[i] = bf(w2[i]);
}

// ---------------- x (b,c,n) f32 -> xT (b,n,c) bf16 ----------------
__global__ __launch_bounds__(256)
void xpose_kernel(const float* __restrict__ x, u16* __restrict__ xT) {
  const int n0 = blockIdx.x * 64, c0 = blockIdx.y * 64, b = blockIdx.z;
  __shared__ float lds[64][65];
  const int t = threadIdx.x;
  const float* xb = x + (size_t)b * C_ * N_;
  const int row = t >> 4, col4 = (t & 15) * 4;
#pragma unroll
  for (int p = 0; p < 4; ++p) {
    float4 v = *(const float4*)&xb[(size_t)(c0 + row + 16 * p) * N_ + n0 + col4];
    lds[row + 16 * p][col4 + 0] = v.x; lds[row + 16 * p][col4 + 1] = v.y;
    lds[row + 16 * p][col4 + 2] = v.z; lds[row + 16 * p][col4 + 3] = v.w;
  }
  __syncthreads();
  const int r = t >> 2, cb = (t & 3) * 16;
  __align__(16) u16 tmp[16];
#pragma unroll
  for (int j = 0; j < 16; ++j) tmp[j] = bf(lds[cb + j][r]);
  u16* o = xT + (size_t)b * N_ * C_ + (size_t)(n0 + r) * C_ + c0 + cb;
  *(uint4*)o = *(uint4*)tmp;
  *(uint4*)(o + 8) = *(uint4*)(tmp + 8);
}

// ---------------- normalize bases; write f32 (d,r), bf16 (d,r), bf16 T (r,d) ----
__global__ __launch_bounds__(256)
void norm_bases_kernel(const float* __restrict__ binit, float* __restrict__ bases,
                       u16* __restrict__ bases_bf, u16* __restrict__ basesT) {
  const int b = blockIdx.x, t = threadIdx.x;
  const int rr = t & 63, dq = t >> 6;
  const float* src = binit + (size_t)b * C_ * R_;
  float* dst = bases + (size_t)b * C_ * R_;
  u16* dbf = bases_bf + (size_t)b * C_ * R_;
  u16* dT  = basesT + (size_t)b * R_ * C_;
  float vals[64];
  float s = 0.f;
#pragma unroll
  for (int i = 0; i < 64; ++i) {
    float v = src[(size_t)(dq + 4 * i) * R_ + rr];
    vals[i] = v; s = fmaf(v, v, s);
  }
  __shared__ float red[4][64];
  red[dq][rr] = s;
  __syncthreads();
  float nrm = fmaxf(sqrtf(red[0][rr] + red[1][rr] + red[2][rr] + red[3][rr]), 1e-12f);
  const float inv = 1.f / nrm;
#pragma unroll
  for (int i = 0; i < 64; ++i) {
    const int d = dq + 4 * i;
    const float v = vals[i] * inv;
    dst[(size_t)d * R_ + rr] = v;
    dbf[(size_t)d * R_ + rr] = bf(v);
    dT[(size_t)rr * C_ + d]  = bf(v);
  }
}

// ---------------- conv via MFMA: 128x128 block tile, 64x64 per wave ----------------
template<bool CONV1>
__global__ __launch_bounds__(256)
void conv_mfma_kernel(const u16* __restrict__ A, const u16* __restrict__ W,
                      const float* __restrict__ bias, u16* __restrict__ h_dn,
                      u16* __restrict__ h_nd, float* __restrict__ of32) {
  const int nb0 = blockIdx.x * 128, ob0 = blockIdx.y * 128, b = blockIdx.z;
  const int t = threadIdx.x, w = t >> 6, lane = t & 63, g = lane >> 4, c = lane & 15;
  const int n_base = nb0 + (w >> 1) * 64, o_base = ob0 + (w & 1) * 64;
  const u16* Ab = A + (size_t)b * N_ * C_;
  f4v acc[4][4] = {};
  for (int k0 = 0; k0 < C_; k0 += 32) {
    bf8v av[4], wv[4];
#pragma unroll
    for (int mi = 0; mi < 4; ++mi)
      av[mi] = ldf(Ab + (size_t)(n_base + mi * 16 + c) * C_ + k0 + g * 8);
#pragma unroll
    for (int nj = 0; nj < 4; ++nj)
      wv[nj] = ldf(W + (size_t)(o_base + nj * 16 + c) * C_ + k0 + g * 8);
#pragma unroll
    for (int mi = 0; mi < 4; ++mi)
#pragma unroll
      for (int nj = 0; nj < 4; ++nj)
        acc[mi][nj] = MFMA(av[mi], wv[nj], acc[mi][nj]);
  }
  __shared__ float lds[64][65];
  for (int p = 0; p < 4; ++p) {
    if (w == p) {
#pragma unroll
      for (int mi = 0; mi < 4; ++mi)
#pragma unroll
        for (int nj = 0; nj < 4; ++nj) {
          const float bb = CONV1 ? bias[o_base + nj * 16 + c] : 0.f;
#pragma unroll
          for (int rg = 0; rg < 4; ++rg) {
            float v = acc[mi][nj][rg];
            if (CONV1) v = fmaxf(v + bb, 0.f);
            lds[mi * 16 + g * 4 + rg][nj * 16 + c] = v;
          }
        }
    }
    __syncthreads();
    const int pn = nb0 + (p >> 1) * 64, po = ob0 + (p & 1) * 64;
    if (CONV1) {
      {
        const int n = t >> 2, ob2 = (t & 3) * 16;
        __align__(16) u16 tmp[16];
#pragma unroll
        for (int j = 0; j < 16; ++j) tmp[j] = bf(lds[n][ob2 + j]);
        u16* o = h_nd + (size_t)b * N_ * C_ + (size_t)(pn + n) * C_ + po + ob2;
        *(uint4*)o = *(uint4*)tmp; *(uint4*)(o + 8) = *(uint4*)(tmp + 8);
      }
      {
        const int oo = t >> 2, nb2 = (t & 3) * 16;
        __align__(16) u16 tmp[16];
#pragma unroll
        for (int j = 0; j < 16; ++j) tmp[j] = bf(lds[nb2 + j][oo]);
        u16* o = h_dn + (size_t)b * C_ * N_ + (size_t)(po + oo) * N_ + pn + nb2;
        *(uint4*)o = *(uint4*)tmp; *(uint4*)(o + 8) = *(uint4*)(tmp + 8);
      }
    } else {
      const int oo = t >> 2, nb2 = (t & 3) * 16;
      float* o = of32 + (size_t)b * C_ * N_ + (size_t)(po + oo) * N_ + pn + nb2;
#pragma unroll
      for (int q = 0; q < 4; ++q) {
        float4 v = make_float4(lds[nb2 + q * 4 + 0][oo], lds[nb2 + q * 4 + 1][oo],
                               lds[nb2 + q * 4 + 2][oo], lds[nb2 + q * 4 + 3][oo]);
        *(float4*)&o[q * 4] = v;
      }
    }
    __syncthreads();
  }
}

// ---------------- fused NMF kernel ----------------
// MODE 0: coef = softmax(h^T bases)
// MODE 1: btb; coef *= (h^T bases)/(coef btb + eps); ctc,xc partials for this n-chunk
// MODE 2: btb; coef update; rec_nd[n,d] = sum_r coef[n,r] bases[d,r]
template<int MODE>
__global__ __launch_bounds__(512)
void nmf_kernel(const u16* __restrict__ h_nd, const u16* __restrict__ h_dn,
                const u16* __restrict__ basesT, const u16* __restrict__ bases_bf,
                u16* __restrict__ coef_bf, u16* __restrict__ rec_nd,
                float* __restrict__ ctcp, float* __restrict__ xcp) {
  const int nc0 = blockIdx.x * NCH_;
  const int b = blockIdx.y;
  const int t = threadIdx.x, w = t >> 6, lane = t & 63, g = lane >> 4, c = lane & 15;
  __shared__ u16 btb_s[64][72];
  __shared__ u16 coef_s[128][72];
  __shared__ u16 coefT_s[64][136];
  const u16* hb = h_nd + (size_t)b * N_ * C_;
  const u16* bT = basesT + (size_t)b * R_ * C_;
  u16* cb = coef_bf + (size_t)b * N_ * R_;

  // Phase A/B: num = h^T bases  (+ btb fused, waves 0..3, MODE!=0)
  f4v num[4] = {};
  f4v bt[4] = {};
  const u16* An = hb + (size_t)(nc0 + w * 16 + c) * C_ + g * 8;
  const u16* Abt = bT + (size_t)(w * 16 + c) * C_ + g * 8;
  for (int k0 = 0; k0 < C_; k0 += 32) {
    bf8v bv[4];
#pragma unroll
    for (int nj = 0; nj < 4; ++nj)
      bv[nj] = ldf(bT + (size_t)(nj * 16 + c) * C_ + k0 + g * 8);
    bf8v a = ldf(An + k0);
#pragma unroll
    for (int nj = 0; nj < 4; ++nj) num[nj] = MFMA(a, bv[nj], num[nj]);
    if (MODE != 0 && w < 4) {
      bf8v a2 = ldf(Abt + k0);
#pragma unroll
      for (int nj = 0; nj < 4; ++nj) bt[nj] = MFMA(a2, bv[nj], bt[nj]);
    }
  }

  if (MODE == 0) {
#pragma unroll
    for (int rg = 0; rg < 4; ++rg) {
      float m = fmaxf(fmaxf(num[0][rg], num[1][rg]), fmaxf(num[2][rg], num[3][rg]));
#pragma unroll
      for (int off = 1; off < 16; off <<= 1) m = fmaxf(m, __shfl_xor(m, off));
      float e[4], s = 0.f;
#pragma unroll
      for (int nj = 0; nj < 4; ++nj) { e[nj] = __expf(num[nj][rg] - m); s += e[nj]; }
#pragma unroll
      for (int off = 1; off < 16; off <<= 1) s += __shfl_xor(s, off);
      const float inv = 1.f / s;
      const int n = nc0 + w * 16 + g * 4 + rg;
#pragma unroll
      for (int nj = 0; nj < 4; ++nj)
        cb[(size_t)n * R_ + nj * 16 + c] = bf(e[nj] * inv);
    }
    return;
  }

  if (w < 4) {
#pragma unroll
    for (int nj = 0; nj < 4; ++nj)
#pragma unroll
      for (int rg = 0; rg < 4; ++rg)
        btb_s[w * 16 + g * 4 + rg][nj * 16 + c] = bf(bt[nj][rg]);
  }
  __syncthreads();

  // Phase C: den = coef_old @ btb  (K = 64)
  f4v den[4] = {};
  const u16* Ac = cb + (size_t)(nc0 + w * 16 + c) * R_ + g * 8;
#pragma unroll
  for (int k0 = 0; k0 < R_; k0 += 32) {
    bf8v a = ldf(Ac + k0);
#pragma unroll
    for (int nj = 0; nj < 4; ++nj) {
      bf8v bb = *(const bf8v*)&btb_s[nj * 16 + c][k0 + g * 8];
      den[nj] = MFMA(a, bb, den[nj]);
    }
  }

  // Phase D: multiplicative update, stash to LDS
#pragma unroll
  for (int nj = 0; nj < 4; ++nj)
#pragma unroll
    for (int rg = 0; rg < 4; ++rg) {
      const int nl = w * 16 + g * 4 + rg, r = nj * 16 + c;
      const float old = bf2f(cb[(size_t)(nc0 + nl) * R_ + r]);
      const u16 nv = bf(old * num[nj][rg] / (den[nj][rg] + EPS_));
      coef_s[nl][r] = nv;
      if (MODE == 1) coefT_s[r][nl] = nv;
    }
  __syncthreads();

  // vectorized global coef write
  {
    const int row = t >> 2, seg = (t & 3) * 16;
    uint4 v0 = *(const uint4*)&coef_s[row][seg];
    uint4 v1 = *(const uint4*)&coef_s[row][seg + 8];
    u16* dst = cb + (size_t)(nc0 + row) * R_ + seg;
    *(uint4*)dst = v0; *(uint4*)(dst + 8) = v1;
  }

  if (MODE == 1) {
    // xc partial: all waves, d rows w*32 + mi*16, K = 128 (local n)
    f4v xa[2][4] = {};
    const u16* hd = h_dn + (size_t)b * C_ * N_;
    for (int k0 = 0; k0 < NCH_; k0 += 32) {
      bf8v bv[4];
#pragma unroll
      for (int nj = 0; nj < 4; ++nj)
        bv[nj] = *(const bf8v*)&coefT_s[nj * 16 + c][k0 + g * 8];
#pragma unroll
      for (int mi = 0; mi < 2; ++mi) {
        bf8v a = ldf(hd + (size_t)(w * 32 + mi * 16 + c) * N_ + nc0 + k0 + g * 8);
#pragma unroll
        for (int nj = 0; nj < 4; ++nj) xa[mi][nj] = MFMA(a, bv[nj], xa[mi][nj]);
      }
    }
    float* xo = xcp + ((size_t)b * NSP_ + blockIdx.x) * (C_ * R_);
#pragma unroll
    for (int mi = 0; mi < 2; ++mi)
#pragma unroll
      for (int nj = 0; nj < 4; ++nj)
#pragma unroll
        for (int rg = 0; rg < 4; ++rg)
          xo[(size_t)(w * 32 + mi * 16 + g * 4 + rg) * R_ + nj * 16 + c] = xa[mi][nj][rg];
    // ctc partial: waves 0..3
    if (w < 4) {
      f4v ca[4] = {};
      for (int k0 = 0; k0 < NCH_; k0 += 32) {
        bf8v a = *(const bf8v*)&coefT_s[w * 16 + c][k0 + g * 8];
#pragma unroll
        for (int nj = 0; nj < 4; ++nj) {
          bf8v bb = *(const bf8v*)&coefT_s[nj * 16 + c][k0 + g * 8];
          ca[nj] = MFMA(a, bb, ca[nj]);
        }
      }
      float* co = ctcp + ((size_t)b * NSP_ + blockIdx.x) * (R_ * R_);
#pragma unroll
      for (int nj = 0; nj < 4; ++nj)
#pragma unroll
        for (int rg = 0; rg < 4; ++rg)
          co[(size_t)(w * 16 + g * 4 + rg) * R_ + nj * 16 + c] = ca[nj][rg];
    }
  }

  if (MODE == 2) {
    // rec_nd[n, d] = sum_r coef[n,r] * bases[d,r]; wave w owns d cols w*32..+31
    f4v ra[8][2] = {};
    const u16* Bb = bases_bf + (size_t)b * C_ * R_;
#pragma unroll
    for (int k0 = 0; k0 < R_; k0 += 32) {
      bf8v bv[2];
#pragma unroll
      for (int nj = 0; nj < 2; ++nj)
        bv[nj] = ldf(Bb + (size_t)(w * 32 + nj * 16 + c) * R_ + k0 + g * 8);
#pragma unroll
      for (int mi = 0; mi < 8; ++mi) {
        bf8v a = *(const bf8v*)&coef_s[mi * 16 + c][k0 + g * 8];
#pragma unroll
        for (int nj = 0; nj < 2; ++nj) ra[mi][nj] = MFMA(a, bv[nj], ra[mi][nj]);
      }
    }
    u16* ro = rec_nd + (size_t)b * N_ * C_;
#pragma unroll
    for (int mi = 0; mi < 8; ++mi)
#pragma unroll
      for (int nj = 0; nj < 2; ++nj)
#pragma unroll
        for (int rg = 0; rg < 4; ++rg)
          ro[(size_t)(nc0 + mi * 16 + g * 4 + rg) * C_ + w * 32 + nj * 16 + c] =
              bf(ra[mi][nj][rg]);
  }
}

// ---------------- bases *= (x coef) / (bases ctc + eps) ----------------
__global__ __launch_bounds__(1024)
void bases_update_kernel(const float* __restrict__ xcp, const float* __restrict__ ctcp,
                         float* __restrict__ bases, u16* __restrict__ bases_bf,
                         u16* __restrict__ basesT) {
  const int dt = blockIdx.x, b = blockIdx.y, d0 = dt * 64;
  float* bb = bases + (size_t)b * C_ * R_;
  __shared__ float ctc_s[64 * 64];
  __shared__ float b_s[64][65];
  const int t = threadIdx.x, tq = t & 15, dd = t >> 4, r0 = tq * 4;
  {
    float4 a = make_float4(0, 0, 0, 0);
    for (int s = 0; s < NSP_; ++s) {
      float4 v = *(const float4*)&ctcp[((size_t)b * NSP_ + s) * (R_ * R_) + t * 4];
      a.x += v.x; a.y += v.y; a.z += v.z; a.w += v.w;
    }
    *(float4*)&ctc_s[t * 4] = a;
  }
  {
    const int lc = t & 63, lr = t >> 6;
#pragma unroll
    for (int p = 0; p < 4; ++p)
      b_s[lr + 16 * p][lc] = bb[(size_t)(d0 + lr + 16 * p) * R_ + lc];
  }
  float4 num2 = make_float4(0, 0, 0, 0);
  for (int s = 0; s < NSP_; ++s) {
    float4 v = *(const float4*)&xcp[(((size_t)b * NSP_ + s) * C_ + d0 + dd) * R_ + r0];
    num2.x += v.x; num2.y += v.y; num2.z += v.z; num2.w += v.w;
  }
  __syncthreads();
  float4 den = make_float4(0, 0, 0, 0);
#pragma unroll
  for (int k = 0; k < 64; ++k) {
    const float a = b_s[dd][k];
    float4 cv = *(const float4*)&ctc_s[k * 64 + r0];
    den.x = fmaf(a, cv.x, den.x); den.y = fmaf(a, cv.y, den.y);
    den.z = fmaf(a, cv.z, den.z); den.w = fmaf(a, cv.w, den.w);
  }
  float4 o;
  o.x = b_s[dd][r0 + 0] * num2.x / (den.x + EPS_);
  o.y = b_s[dd][r0 + 1] * num2.y / (den.y + EPS_);
  o.z = b_s[dd][r0 + 2] * num2.z / (den.z + EPS_);
  o.w = b_s[dd][r0 + 3] * num2.w / (den.w + EPS_);
  *(float4*)&bb[(size_t)(d0 + dd) * R_ + r0] = o;
  u16* obf = bases_bf + (size_t)b * C_ * R_ + (size_t)(d0 + dd) * R_ + r0;
  obf[0] = bf(o.x); obf[1] = bf(o.y); obf[2] = bf(o.z); obf[3] = bf(o.w);
  u16* oT = basesT + (size_t)b * R_ * C_ + d0 + dd;
  oT[(size_t)(r0 + 0) * C_] = bf(o.x); oT[(size_t)(r0 + 1) * C_] = bf(o.y);
  oT[(size_t)(r0 + 2) * C_] = bf(o.z); oT[(size_t)(r0 + 3) * C_] = bf(o.w);
}

// ---------------- GroupNorm stats ----------------
__global__ __launch_bounds__(256)
void gn_stats_kernel(const float* __restrict__ o, float* __restrict__ stats) {
  const int g = blockIdx.x, b = blockIdx.y;
  const float* p = o + ((size_t)b * C_ + g * 8) * N_;
  const int t = threadIdx.x;
  float s = 0.f, s2 = 0.f;
  for (int i = t; i < 8192; i += 256) {
    float4 v = ((const float4*)p)[i];
    s += v.x + v.y + v.z + v.w;
    s2 = fmaf(v.x, v.x, s2); s2 = fmaf(v.y, v.y, s2);
    s2 = fmaf(v.z, v.z, s2); s2 = fmaf(v.w, v.w, s2);
  }
#pragma unroll
  for (int off = 32; off > 0; off >>= 1) { s += __shfl_down(s, off); s2 += __shfl_down(s2, off); }
  __shared__ float rs[4], rs2[4];
  if ((t & 63) == 0) { rs[t >> 6] = s; rs2[t >> 6] = s2; }
  __syncthreads();
  if (t == 0) {
    float S = rs[0] + rs[1] + rs[2] + rs[3];
    float S2 = rs2[0] + rs2[1] + rs2[2] + rs2[3];
    float mean = S / 32768.f;
    float var = S2 / 32768.f - mean * mean;
    stats[(b * 32 + g) * 2 + 0] = mean;
    stats[(b * 32 + g) * 2 + 1] = rsqrtf(var + 1e-5f);
  }
}

// ---------------- GN affine + residual + relu ----------------
__global__ __launch_bounds__(256)
void gn_final_kernel(const float* __restrict__ x, const float* __restrict__ gamma,
                     const float* __restrict__ beta, const float* __restrict__ stats,
                     float* __restrict__ out) {
  const size_t gid = (size_t)blockIdx.x * 256 + threadIdx.x;
  const size_t idx = gid * 4;
  const int b = (int)(idx >> 20);
  const int rem = (int)(idx & ((1u << 20) - 1));
  const int c = rem >> 12;
  const int g = c >> 3;
  const float mean = stats[(b * 32 + g) * 2 + 0];
  const float rstd = stats[(b * 32 + g) * 2 + 1];
  const float ga = gamma[c] * rstd;
  const float be = beta[c] - mean * ga;
  float4 ov = ((const float4*)out)[gid];
  float4 xv = ((const float4*)x)[gid];
  float4 r;
  r.x = fmaxf(fmaf(ov.x, ga, be) + xv.x, 0.f);
  r.y = fmaxf(fmaf(ov.y, ga, be) + xv.y, 0.f);
  r.z = fmaxf(fmaf(ov.z, ga, be) + xv.z, 0.f);
  r.w = fmaxf(fmaf(ov.w, ga, be) + xv.w, 0.f);
  ((float4*)out)[gid] = r;
}

extern "C" void kernel_launch(void* const* d_in, const int* in_sizes, int n_in,
                              void* d_out, int out_size, void* d_ws, size_t ws_size,
                              hipStream_t stream) {
  (void)in_sizes; (void)n_in; (void)out_size; (void)ws_size;
  const float* x     = (const float*)d_in[0];
  const float* w_in  = (const float*)d_in[1];
  const float* b_in  = (const float*)d_in[2];
  const float* w_out = (const float*)d_in[3];
  const float* gamma = (const float*)d_in[4];
  const float* beta  = (const float*)d_in[5];
  const float* binit = (const float*)d_in[6];
  float* out = (float*)d_out;

  float* p = (float*)d_ws;
  u16* xT = (u16*)p;        p += 4194304;   // B*N*C bf16; reused as rec_nd
  u16* rec_nd = xT;
  u16* h_nd = (u16*)p;      p += 4194304;   // B*N*C bf16
  u16* h_dn = (u16*)p;      p += 4194304;   // B*C*N bf16
  u16* coef_bf = (u16*)p;   p += 1048576;   // B*N*R bf16
  float* bases = p;         p += 131072;    // B*C*R f32
  u16* bases_bf = (u16*)p;  p += 65536;
  u16* basesT = (u16*)p;    p += 65536;
  float* ctcp = p;          p += 1048576;   // B*NSP*R*R f32
  float* xcp = p;           p += 4194304;   // B*NSP*C*R f32
  u16* w1b = (u16*)p;       p += 32768;     // C*C bf16 = 65536 u16 = 32768 floats
  u16* w2b = (u16*)p;       p += 32768;     // C*C bf16 = 65536 u16 = 32768 floats
  float* stats = p;         p += 512;

  cvt_w_kernel<<<dim3(256), 256, 0, stream>>>(w_in, w_out, w1b, w2b);
  xpose_kernel<<<dim3(64, 4, 8), 256, 0, stream>>>(x, xT);
  norm_bases_kernel<<<dim3(B_), 256, 0, stream>>>(binit, bases, bases_bf, basesT);
  conv_mfma_kernel<true><<<dim3(32, 2, 8), 256, 0, stream>>>(xT, w1b, b_in, h_dn, h_nd, nullptr);
  nmf_kernel<0><<<dim3(32, 8), 512, 0, stream>>>(h_nd, h_dn, basesT, bases_bf, coef_bf,
                                                 nullptr, nullptr, nullptr);
  for (int it = 0; it < STEPS_; ++it) {
    nmf_kernel<1><<<dim3(32, 8), 512, 0, stream>>>(h_nd, h_dn, basesT, bases_bf, coef_bf,
                                                   nullptr, ctcp, xcp);
    bases_update_kernel<<<dim3(4, 8), 1024, 0, stream>>>(xcp, ctcp, bases, bases_bf, basesT);
  }
  nmf_kernel<2><<<dim3(32, 8), 512, 0, stream>>>(h_nd, h_dn, basesT, bases_bf, coef_bf,
                                                 rec_nd, nullptr, nullptr);
  conv_mfma_kernel<false><<<dim3(32, 2, 8), 256, 0, stream>>>(rec_nd, w2b, nullptr,
                                                              nullptr, nullptr, out);
  gn_stats_kernel<<<dim3(32, 8), 256, 0, stream>>>(out, stats);
  gn_final_kernel<<<dim3((B_ * C_ * N_) / 4 / 256), 256, 0, stream>>>(x, gamma, beta, stats, out);
}